// Round 22
// baseline (1704.403 us; speedup 1.0000x reference)
//
#include <hip/hip_runtime.h>

#define BSZ 2048
#define SEQ 50
#define HID 128
#define NHEAD 4
#define HDIM 32
#define INNER 512
#define NITEMS 50000
#define NOUT 49999
#define NPAD3 51200
#define NROWS (BSZ*SEQ)

typedef float f32x4 __attribute__((ext_vector_type(4)));
typedef short s16x8 __attribute__((ext_vector_type(8)));

__device__ __forceinline__ unsigned short f2b(float f){
  unsigned int u = __builtin_bit_cast(unsigned int, f);
  u = (u + 0x7FFFu + ((u >> 16) & 1u)) >> 16;
  return (unsigned short)u;
}
__device__ __forceinline__ float b2f(unsigned short h){
  unsigned int u = ((unsigned int)h) << 16;
  return __builtin_bit_cast(float, u);
}
// fragment-major packed offset: (n,k) with K/32 = ksteps.
// lane (g,c16) of frag (tile,kt) reads 8 consecutive ushorts at
// (tile*ksteps+kt)*512 + lane*8  (lane = g*16 + c16).
__device__ __forceinline__ size_t pk(int n, int k, int ksteps){
  return ((size_t)((n >> 4)*ksteps + (k >> 5))*64 + ((k >> 3) & 3)*16 + (n & 15))*8 + (k & 7);
}

__global__ void embed_k(const int* __restrict__ ids, const float* __restrict__ emb,
                        const float* __restrict__ pos, float* __restrict__ x){
  int row = blockIdx.x;          // b*SEQ + l
  int l = row % SEQ;
  int t = threadIdx.x;
  int id = ids[row];
  x[(size_t)row*HID + t] = emb[(size_t)id*HID + t] + pos[l*HID + t];
}

// split W1/W2 into bf16 hi/lo pairs, fragment-major packed.
__global__ void cvtw2_k(const float* __restrict__ W1, const float* __restrict__ W2,
                        unsigned short* __restrict__ W1h, unsigned short* __restrict__ W1l,
                        unsigned short* __restrict__ W2h, unsigned short* __restrict__ W2l){
  int i = blockIdx.x*256 + threadIdx.x;   // 0..131071
  {
    int l = i >> 16, rc = i & 65535;
    int n = rc >> 7, k = rc & 127;          // W1 [512][128]
    float w = W1[i];
    unsigned short h = f2b(w);
    size_t off = (size_t)l*65536 + pk(n, k, 4);
    W1h[off] = h; W1l[off] = f2b(w - b2f(h));
  }
  {
    int l = i >> 16, rc = i & 65535;
    int n = rc >> 9, k = rc & 511;          // W2 [128][512]
    float w = W2[i];
    unsigned short h = f2b(w);
    size_t off = (size_t)l*65536 + pk(n, k, 16);
    W2h[off] = h; W2l[off] = f2b(w - b2f(h));
  }
}

// Wq/Wk/Wv stacked [2][384][128] packed; Wo [2][128][128] packed.
__global__ void cvtw_qkvo_k(const float* __restrict__ Wq, const float* __restrict__ Wk,
                            const float* __restrict__ Wv, const float* __restrict__ Wo,
                            unsigned short* __restrict__ dst){
  int i = blockIdx.x*256 + threadIdx.x;   // 0..32767
  int l = i >> 14;
  int rc = i & 16383;
  int r = rc >> 7, k = rc & 127;
  unsigned short* Wqkvh = dst;
  unsigned short* Wqkvl = dst + 98304;
  unsigned short* Woh   = dst + 196608;
  unsigned short* Wol   = dst + 229376;
  size_t base = (size_t)l*49152;
  float w; unsigned short h;
  w = Wq[i]; h = f2b(w);
  { size_t o = base + pk(r, k, 4);        Wqkvh[o] = h; Wqkvl[o] = f2b(w - b2f(h)); }
  w = Wk[i]; h = f2b(w);
  { size_t o = base + pk(128 + r, k, 4);  Wqkvh[o] = h; Wqkvl[o] = f2b(w - b2f(h)); }
  w = Wv[i]; h = f2b(w);
  { size_t o = base + pk(256 + r, k, 4);  Wqkvh[o] = h; Wqkvl[o] = f2b(w - b2f(h)); }
  w = Wo[i]; h = f2b(w);
  { size_t o = (size_t)l*16384 + pk(r, k, 4); Woh[o] = h; Wol[o] = f2b(w - b2f(h)); }
}

// mixW [2][128][256] -> hi/lo packed (ksteps=8)
__global__ void cvtmix_k(const float* __restrict__ mixW,
                         unsigned short* __restrict__ mWh, unsigned short* __restrict__ mWl){
  int i = blockIdx.x*256 + threadIdx.x;   // 0..65535
  int l = i >> 15, rc = i & 32767;
  int n = rc >> 8, k = rc & 255;
  float w = mixW[i];
  unsigned short h = f2b(w);
  size_t off = (size_t)l*32768 + pk(n, k, 8);
  mWh[off] = h; mWl[off] = f2b(w - b2f(h));
}

// sess plain hi/lo; emb packed hi/lo (zero-padded to NPAD3, ksteps=4).
__global__ void cvt_logits_k(const float* __restrict__ sess, const float* __restrict__ emb,
                             unsigned short* __restrict__ sessH, unsigned short* __restrict__ sessL,
                             unsigned short* __restrict__ embH, unsigned short* __restrict__ embL){
  int i = blockIdx.x*256 + threadIdx.x;   // 0 .. NPAD3*128-1
  int n = i >> 7, k = i & 127;
  float w = (n < NOUT) ? emb[(size_t)(1+n)*HID + k] : 0.f;
  unsigned short h = f2b(w);
  size_t off = pk(n, k, 4);
  embH[off] = h; embL[off] = f2b(w - b2f(h));
  if (i < BSZ*HID){
    float s = sess[i];
    unsigned short hs = f2b(s);
    sessH[i] = hs; sessL[i] = f2b(s - b2f(hs));
  }
}

// mix via MFMA (R11 structure); epilogue also writes x in packed hi/lo for qkv.
__global__ __launch_bounds__(256) void mix_mfma_k(
    const float* __restrict__ A, const float* __restrict__ x,
    const unsigned short* __restrict__ mWh, const unsigned short* __restrict__ mWl,
    const float* __restrict__ mixb, float* __restrict__ xout,
    unsigned short* __restrict__ xPh, unsigned short* __restrict__ xPl)
{
  __shared__ __align__(16) char smem[65536];
  char* xTh = smem;
  char* xTl = smem + 16384;
  char* Ah  = smem + 32768;
  char* Al  = smem + 49152;
  char* Ch  = smem;
  char* Cl  = smem + 32768;

  int t = threadIdx.x;
  int wave = t >> 6, lane = t & 63;
  int g = lane >> 4, c16 = lane & 15;
  int b = blockIdx.x;
  size_t xbase = (size_t)b * SEQ * HID;

  {
    s16x8 z = {0,0,0,0,0,0,0,0};
    #pragma unroll
    for (int it = 0; it < 16; ++it)
      *(s16x8*)(smem + (it*256 + t)*16) = z;
  }
  __syncthreads();

  for (int task = t; task < SEQ*32; task += 256){
    int r = task >> 5, c4 = task & 31;
    float4 v = *(const float4*)(x + xbase + (size_t)r*HID + c4*4);
    float f[4] = {v.x, v.y, v.z, v.w};
    #pragma unroll
    for (int i = 0; i < 4; ++i){
      int d = c4*4 + i;
      unsigned short hi = f2b(f[i]);
      unsigned short lo = f2b(f[i] - b2f(hi));
      int off = d*128 + ((((r >> 3) ^ (d & 7))<<4)) + (r & 7)*2;
      *(unsigned short*)(xTh + off) = hi;
      *(unsigned short*)(xTl + off) = lo;
    }
  }
  {
    int l = t >> 2, q = t & 3;
    if (l < SEQ){
      const float* Ar = A + (size_t)(b*SEQ + l)*100;
      for (int j = q*25; j < q*25 + 25; ++j){
        float av = Ar[j];
        int col = (j < SEQ) ? j : (64 + (j - SEQ));
        unsigned short hi = f2b(av);
        unsigned short lo = f2b(av - b2f(hi));
        int off = l*256 + ((((col >> 3) ^ (l & 15))<<4)) + (col & 7)*2;
        *(unsigned short*)(Ah + off) = hi;
        *(unsigned short*)(Al + off) = lo;
      }
    }
  }
  __syncthreads();

  int rA = wave*16 + c16;
  s16x8 aih[2], ail[2], aoh[2], aol[2];
  #pragma unroll
  for (int kt = 0; kt < 2; ++kt){
    int ci = kt*4 + g;
    int co = 8 + kt*4 + g;
    int offi = rA*256 + ((ci ^ (rA & 15))<<4);
    int offo = rA*256 + ((co ^ (rA & 15))<<4);
    aih[kt] = *(const s16x8*)(Ah + offi);
    ail[kt] = *(const s16x8*)(Al + offi);
    aoh[kt] = *(const s16x8*)(Ah + offo);
    aol[kt] = *(const s16x8*)(Al + offo);
  }
  f32x4 accin[8], accout[8];
  #pragma unroll
  for (int nt = 0; nt < 8; ++nt){ accin[nt] = (f32x4){0,0,0,0}; accout[nt] = (f32x4){0,0,0,0}; }
  #pragma unroll
  for (int kt = 0; kt < 2; ++kt){
    #pragma unroll
    for (int nt = 0; nt < 8; ++nt){
      int d = nt*16 + c16;
      int boff = d*128 + ((((kt*4 + g) ^ (d & 7)))<<4);
      s16x8 bh = *(const s16x8*)(xTh + boff);
      s16x8 bl = *(const s16x8*)(xTl + boff);
      accin[nt]  = __builtin_amdgcn_mfma_f32_16x16x32_bf16(aih[kt], bh, accin[nt], 0,0,0);
      accin[nt]  = __builtin_amdgcn_mfma_f32_16x16x32_bf16(aih[kt], bl, accin[nt], 0,0,0);
      accin[nt]  = __builtin_amdgcn_mfma_f32_16x16x32_bf16(ail[kt], bh, accin[nt], 0,0,0);
      accout[nt] = __builtin_amdgcn_mfma_f32_16x16x32_bf16(aoh[kt], bh, accout[nt], 0,0,0);
      accout[nt] = __builtin_amdgcn_mfma_f32_16x16x32_bf16(aoh[kt], bl, accout[nt], 0,0,0);
      accout[nt] = __builtin_amdgcn_mfma_f32_16x16x32_bf16(aol[kt], bh, accout[nt], 0,0,0);
    }
  }
  __syncthreads();

  #pragma unroll
  for (int nt = 0; nt < 8; ++nt){
    #pragma unroll
    for (int r = 0; r < 4; ++r){
      int l = wave*16 + g*4 + r;
      int ci_ = nt*16 + c16;
      float vi = accin[nt][r];
      unsigned short hi = f2b(vi);
      int offi = l*512 + (((ci_ >> 3) ^ (l & 15))<<4) + (ci_ & 7)*2;
      *(unsigned short*)(Ch + offi) = hi;
      *(unsigned short*)(Cl + offi) = f2b(vi - b2f(hi));
      int co_ = 128 + nt*16 + c16;
      float vo = accout[nt][r];
      unsigned short ho = f2b(vo);
      int offo = l*512 + (((co_ >> 3) ^ (l & 15))<<4) + (co_ & 7)*2;
      *(unsigned short*)(Ch + offo) = ho;
      *(unsigned short*)(Cl + offo) = f2b(vo - b2f(ho));
    }
  }
  __syncthreads();

  int rc = wave*16 + c16;
  f32x4 acc2[8];
  #pragma unroll
  for (int nt = 0; nt < 8; ++nt) acc2[nt] = (f32x4){0,0,0,0};
  for (int kt2 = 0; kt2 < 8; ++kt2){
    int slot = (kt2*4 + g) ^ (rc & 15);
    s16x8 cfh = *(const s16x8*)(Ch + rc*512 + slot*16);
    s16x8 cfl = *(const s16x8*)(Cl + rc*512 + slot*16);
    #pragma unroll
    for (int nt = 0; nt < 8; ++nt){
      s16x8 wh = *(const s16x8*)(mWh + (size_t)(nt*8 + kt2)*512 + lane*8);
      s16x8 wl = *(const s16x8*)(mWl + (size_t)(nt*8 + kt2)*512 + lane*8);
      acc2[nt] = __builtin_amdgcn_mfma_f32_16x16x32_bf16(cfh, wh, acc2[nt], 0,0,0);
      acc2[nt] = __builtin_amdgcn_mfma_f32_16x16x32_bf16(cfh, wl, acc2[nt], 0,0,0);
      acc2[nt] = __builtin_amdgcn_mfma_f32_16x16x32_bf16(cfl, wh, acc2[nt], 0,0,0);
    }
  }
  #pragma unroll
  for (int nt = 0; nt < 8; ++nt){
    int j = nt*16 + c16;
    float bb = mixb[j];
    #pragma unroll
    for (int r = 0; r < 4; ++r){
      int l = wave*16 + g*4 + r;
      if (l < SEQ){
        float v = acc2[nt][r] + bb;
        xout[xbase + (size_t)l*HID + j] = v;
        int gr = b*SEQ + l;
        unsigned short hh = f2b(v);
        size_t po = pk(gr, j, 4);
        xPh[po] = hh; xPl[po] = f2b(v - b2f(hh));
      }
    }
  }
}

// QKV projection: packed A-frags direct from global (no LDS, no barrier).
__global__ __launch_bounds__(256) void qkv_mfma_k(
    const unsigned short* __restrict__ xPh, const unsigned short* __restrict__ xPl,
    const unsigned short* __restrict__ Wh, const unsigned short* __restrict__ Wl,
    const float* __restrict__ bq, const float* __restrict__ bk,
    const float* __restrict__ bv, float* __restrict__ qkv)
{
  int t = threadIdx.x;
  int wave = t >> 6, lane = t & 63;
  int g = lane >> 4, c16 = lane & 15;
  int wrh = wave >> 1;
  int wn  = wave & 1;
  size_t row0 = (size_t)blockIdx.x * 64;
  int rt0 = (int)(row0 >> 4) + wrh;   // group0 row-tile; group1 = +2

  s16x8 a0h[4], a0l[4], a1h[4], a1l[4];
  #pragma unroll
  for (int kt = 0; kt < 4; ++kt){
    a0h[kt] = *(const s16x8*)(xPh + (size_t)(rt0*4 + kt)*512 + lane*8);
    a0l[kt] = *(const s16x8*)(xPl + (size_t)(rt0*4 + kt)*512 + lane*8);
    a1h[kt] = *(const s16x8*)(xPh + (size_t)((rt0+2)*4 + kt)*512 + lane*8);
    a1l[kt] = *(const s16x8*)(xPl + (size_t)((rt0+2)*4 + kt)*512 + lane*8);
  }

  for (int nt = 0; nt < 12; ++nt){
    int tile = wn*12 + nt;
    int ncol = tile*16 + c16;          // 0..383
    f32x4 acc0 = {0.f,0.f,0.f,0.f};
    f32x4 acc1 = {0.f,0.f,0.f,0.f};
    #pragma unroll
    for (int kt = 0; kt < 4; ++kt){
      s16x8 bh = *(const s16x8*)(Wh + (size_t)(tile*4 + kt)*512 + lane*8);
      s16x8 bl = *(const s16x8*)(Wl + (size_t)(tile*4 + kt)*512 + lane*8);
      acc0 = __builtin_amdgcn_mfma_f32_16x16x32_bf16(a0h[kt], bh, acc0, 0,0,0);
      acc0 = __builtin_amdgcn_mfma_f32_16x16x32_bf16(a0h[kt], bl, acc0, 0,0,0);
      acc0 = __builtin_amdgcn_mfma_f32_16x16x32_bf16(a0l[kt], bh, acc0, 0,0,0);
      acc1 = __builtin_amdgcn_mfma_f32_16x16x32_bf16(a1h[kt], bh, acc1, 0,0,0);
      acc1 = __builtin_amdgcn_mfma_f32_16x16x32_bf16(a1h[kt], bl, acc1, 0,0,0);
      acc1 = __builtin_amdgcn_mfma_f32_16x16x32_bf16(a1l[kt], bh, acc1, 0,0,0);
    }
    int mat = ncol >> 7;
    int colin = ncol & 127;
    float bias = (mat == 0) ? bq[colin] : (mat == 1 ? bk[colin] : bv[colin]);
    #pragma unroll
    for (int r = 0; r < 4; ++r){
      int m = wrh*16 + g*4 + r;
      qkv[(row0 + m)*384 + ncol] = acc0[r] + bias;
      qkv[(row0 + 32 + m)*384 + ncol] = acc1[r] + bias;
    }
  }
}

// Attention core (proven VALU structure); o written packed hi/lo for oproj.
__global__ void attn_core_k(const float* __restrict__ qkv,
                            unsigned short* __restrict__ oPh,
                            unsigned short* __restrict__ oPl){
  int blk = blockIdx.x; int b = blk / NHEAD; int h = blk % NHEAD;
  int t = threadIdx.x;
  __shared__ float qs[SEQ][HDIM];
  __shared__ float ks[SEQ][HDIM];
  __shared__ float vs[SEQ][HDIM];
  __shared__ float ss[SEQ][SEQ+2];
  size_t base = (size_t)b*SEQ*384 + h*HDIM;
  for (int task = t; task < SEQ*HDIM; task += 256){
    int l = task >> 5, d = task & 31;
    const float* p = qkv + base + (size_t)l*384 + d;
    qs[l][d] = p[0];
    ks[l][d] = p[128];
    vs[l][d] = p[256];
  }
  __syncthreads();
  for (int task = t; task < SEQ*SEQ; task += 256){
    int l = task / SEQ, m = task % SEQ;
    float a = 0.f;
    #pragma unroll
    for (int d = 0; d < HDIM; ++d) a += qs[l][d]*ks[m][d];
    ss[l][m] = a * 0.17677669529663687f;  // 1/sqrt(32)
  }
  __syncthreads();
  if (t < SEQ){
    float mx = -1e30f;
    for (int m = 0; m < SEQ; ++m) mx = fmaxf(mx, ss[t][m]);
    float sum = 0.f;
    for (int m = 0; m < SEQ; ++m){ float e = __expf(ss[t][m]-mx); ss[t][m]=e; sum+=e; }
    float inv = 1.f/sum;
    for (int m = 0; m < SEQ; ++m) ss[t][m] *= inv;
  }
  __syncthreads();
  for (int task = t; task < SEQ*HDIM; task += 256){
    int l = task >> 5, d = task & 31;
    float a = 0.f;
    for (int m = 0; m < SEQ; ++m) a += ss[l][m]*vs[m][d];
    int gr = b*SEQ + l;
    int k = h*HDIM + d;
    unsigned short hh = f2b(a);
    size_t po = pk(gr, k, 4);
    oPh[po] = hh; oPl[po] = f2b(a - b2f(hh));
  }
}

// O @ Wo^T + bo + residual + LN1: packed A-frags direct (no staging);
// epilogue writes fp32 x AND packed xQ for ffn1.
__global__ __launch_bounds__(256) void oproj_mfma_k(
    const unsigned short* __restrict__ oPh, const unsigned short* __restrict__ oPl,
    const unsigned short* __restrict__ Woh_, const unsigned short* __restrict__ Wol_,
    const float* __restrict__ bo, const float* __restrict__ g1,
    const float* __restrict__ be1, float* x,
    unsigned short* __restrict__ xQh, unsigned short* __restrict__ xQl)
{
  __shared__ float red_s[2][2][2][16];
  __shared__ float red_q[2][2][2][16];
  int t = threadIdx.x;
  int wave = t >> 6, lane = t & 63;
  int g = lane >> 4, c16 = lane & 15;
  int wrh = wave >> 1;
  int wn  = wave & 1;
  size_t row0 = (size_t)blockIdx.x * 64;
  int rt0 = (int)(row0 >> 4) + wrh;

  s16x8 a0h[4], a0l[4], a1h[4], a1l[4];
  #pragma unroll
  for (int kt = 0; kt < 4; ++kt){
    a0h[kt] = *(const s16x8*)(oPh + (size_t)(rt0*4 + kt)*512 + lane*8);
    a0l[kt] = *(const s16x8*)(oPl + (size_t)(rt0*4 + kt)*512 + lane*8);
    a1h[kt] = *(const s16x8*)(oPh + (size_t)((rt0+2)*4 + kt)*512 + lane*8);
    a1l[kt] = *(const s16x8*)(oPl + (size_t)((rt0+2)*4 + kt)*512 + lane*8);
  }

  float vals[2][4][4];
  #pragma unroll
  for (int nt = 0; nt < 4; ++nt){
    int tile = wn*4 + nt;
    int jcol = tile*16 + c16;
    f32x4 acc0 = {0.f,0.f,0.f,0.f};
    f32x4 acc1 = {0.f,0.f,0.f,0.f};
    #pragma unroll
    for (int kt = 0; kt < 4; ++kt){
      s16x8 bh = *(const s16x8*)(Woh_ + (size_t)(tile*4 + kt)*512 + lane*8);
      s16x8 bl = *(const s16x8*)(Wol_ + (size_t)(tile*4 + kt)*512 + lane*8);
      acc0 = __builtin_amdgcn_mfma_f32_16x16x32_bf16(a0h[kt], bh, acc0, 0,0,0);
      acc0 = __builtin_amdgcn_mfma_f32_16x16x32_bf16(a0h[kt], bl, acc0, 0,0,0);
      acc0 = __builtin_amdgcn_mfma_f32_16x16x32_bf16(a0l[kt], bh, acc0, 0,0,0);
      acc1 = __builtin_amdgcn_mfma_f32_16x16x32_bf16(a1h[kt], bh, acc1, 0,0,0);
      acc1 = __builtin_amdgcn_mfma_f32_16x16x32_bf16(a1h[kt], bl, acc1, 0,0,0);
      acc1 = __builtin_amdgcn_mfma_f32_16x16x32_bf16(a1l[kt], bh, acc1, 0,0,0);
    }
    float bias = bo[jcol];
    #pragma unroll
    for (int r = 0; r < 4; ++r){
      int m = wrh*16 + g*4 + r;
      vals[0][nt][r] = acc0[r] + bias + x[(row0 + m)*HID + jcol];
      vals[1][nt][r] = acc1[r] + bias + x[(row0 + 32 + m)*HID + jcol];
    }
  }

  #pragma unroll
  for (int q_ = 0; q_ < 2; ++q_){
    #pragma unroll
    for (int r = 0; r < 4; ++r){
      float s_ = vals[q_][0][r] + vals[q_][1][r] + vals[q_][2][r] + vals[q_][3][r];
      float qq = vals[q_][0][r]*vals[q_][0][r] + vals[q_][1][r]*vals[q_][1][r]
               + vals[q_][2][r]*vals[q_][2][r] + vals[q_][3][r]*vals[q_][3][r];
      s_ += __shfl_xor(s_, 1, 64); qq += __shfl_xor(qq, 1, 64);
      s_ += __shfl_xor(s_, 2, 64); qq += __shfl_xor(qq, 2, 64);
      s_ += __shfl_xor(s_, 4, 64); qq += __shfl_xor(qq, 4, 64);
      s_ += __shfl_xor(s_, 8, 64); qq += __shfl_xor(qq, 8, 64);
      if (c16 == 0){
        red_s[q_][wrh][wn][g*4 + r] = s_;
        red_q[q_][wrh][wn][g*4 + r] = qq;
      }
    }
  }
  __syncthreads();
  #pragma unroll
  for (int q_ = 0; q_ < 2; ++q_){
    #pragma unroll
    for (int r = 0; r < 4; ++r){
      int m = wrh*16 + g*4 + r;
      float s_tot = red_s[q_][wrh][0][g*4 + r] + red_s[q_][wrh][1][g*4 + r];
      float q_tot = red_q[q_][wrh][0][g*4 + r] + red_q[q_][wrh][1][g*4 + r];
      float mean = s_tot * (1.f/HID);
      float var = q_tot * (1.f/HID) - mean*mean;
      float rstd = rsqrtf(var + 1e-5f);
      #pragma unroll
      for (int nt = 0; nt < 4; ++nt){
        int jcol = (wn*4 + nt)*16 + c16;
        int grow = (int)row0 + q_*32 + m;
        float v = (vals[q_][nt][r]-mean)*rstd*g1[jcol] + be1[jcol];
        x[(size_t)grow*HID + jcol] = v;
        unsigned short hh = f2b(v);
        size_t po = pk(grow, jcol, 4);
        xQh[po] = hh; xQl[po] = f2b(v - b2f(hh));
      }
    }
  }
}

// FFN part 1: packed A-frags direct from xQ (no staging); H written packed.
__global__ __launch_bounds__(256) void ffn1_k(
    const unsigned short* __restrict__ xQh, const unsigned short* __restrict__ xQl,
    const unsigned short* __restrict__ W1h, const unsigned short* __restrict__ W1l,
    const float* __restrict__ b1,
    unsigned short* __restrict__ Hph, unsigned short* __restrict__ Hpl)
{
  int t = threadIdx.x;
  int wave = t >> 6, lane = t & 63;
  int g = lane >> 4, c16 = lane & 15;
  int wrh = wave >> 1;
  int wn  = wave & 1;
  size_t row0 = (size_t)blockIdx.x * 64;
  int rt0 = (int)(row0 >> 4) + wrh;

  s16x8 a0h[4], a0l[4], a1h[4], a1l[4];
  #pragma unroll
  for (int kt = 0; kt < 4; ++kt){
    a0h[kt] = *(const s16x8*)(xQh + (size_t)(rt0*4 + kt)*512 + lane*8);
    a0l[kt] = *(const s16x8*)(xQl + (size_t)(rt0*4 + kt)*512 + lane*8);
    a1h[kt] = *(const s16x8*)(xQh + (size_t)((rt0+2)*4 + kt)*512 + lane*8);
    a1l[kt] = *(const s16x8*)(xQl + (size_t)((rt0+2)*4 + kt)*512 + lane*8);
  }

  for (int nt = 0; nt < 16; ++nt){
    int tile = wn*16 + nt;
    int ncol = tile*16 + c16;
    f32x4 acc0 = {0.f,0.f,0.f,0.f};
    f32x4 acc1 = {0.f,0.f,0.f,0.f};
    #pragma unroll
    for (int kt = 0; kt < 4; ++kt){
      s16x8 bh = *(const s16x8*)(W1h + (size_t)(tile*4 + kt)*512 + lane*8);
      s16x8 bl = *(const s16x8*)(W1l + (size_t)(tile*4 + kt)*512 + lane*8);
      acc0 = __builtin_amdgcn_mfma_f32_16x16x32_bf16(a0h[kt], bh, acc0, 0,0,0);
      acc0 = __builtin_amdgcn_mfma_f32_16x16x32_bf16(a0h[kt], bl, acc0, 0,0,0);
      acc0 = __builtin_amdgcn_mfma_f32_16x16x32_bf16(a0l[kt], bh, acc0, 0,0,0);
      acc1 = __builtin_amdgcn_mfma_f32_16x16x32_bf16(a1h[kt], bh, acc1, 0,0,0);
      acc1 = __builtin_amdgcn_mfma_f32_16x16x32_bf16(a1h[kt], bl, acc1, 0,0,0);
      acc1 = __builtin_amdgcn_mfma_f32_16x16x32_bf16(a1l[kt], bh, acc1, 0,0,0);
    }
    float bias = b1[ncol];
    #pragma unroll
    for (int r = 0; r < 4; ++r){
      int m0 = (int)row0 + wrh*16 + g*4 + r;
      float h0 = fmaxf(acc0[r] + bias, 0.f);
      unsigned short hh0 = f2b(h0);
      size_t o0 = pk(m0, ncol, 16);
      Hph[o0] = hh0; Hpl[o0] = f2b(h0 - b2f(hh0));
      float h1 = fmaxf(acc1[r] + bias, 0.f);
      unsigned short hh1 = f2b(h1);
      size_t o1 = pk(m0 + 32, ncol, 16);
      Hph[o1] = hh1; Hpl[o1] = f2b(h1 - b2f(hh1));
    }
  }
}

// FFN part 2: packed H + packed W2 frags direct from global (proven R21).
__global__ __launch_bounds__(256) void ffn2_k(
    const unsigned short* __restrict__ Hph, const unsigned short* __restrict__ Hpl,
    const unsigned short* __restrict__ W2h, const unsigned short* __restrict__ W2l,
    const float* __restrict__ b2, const float* __restrict__ gam,
    const float* __restrict__ bet, float* x)
{
  __shared__ float red_s[2][2][16];
  __shared__ float red_q[2][2][16];
  int t = threadIdx.x;
  int wave = t >> 6, lane = t & 63;
  int g = lane >> 4, c16 = lane & 15;
  int wrh = wave >> 1;
  int wn  = wave & 1;
  size_t row0 = (size_t)blockIdx.x * 32;
  int rt = (int)(row0 >> 4) + wrh;     // global 16-row tile of H

  f32x4 acc2[4];
  #pragma unroll
  for (int i = 0; i < 4; ++i) acc2[i] = (f32x4){0.f,0.f,0.f,0.f};
  for (int kt2 = 0; kt2 < 16; ++kt2){
    s16x8 hfh = *(const s16x8*)(Hph + (size_t)(rt*16 + kt2)*512 + lane*8);
    s16x8 hfl = *(const s16x8*)(Hpl + (size_t)(rt*16 + kt2)*512 + lane*8);
    #pragma unroll
    for (int nt2 = 0; nt2 < 4; ++nt2){
      int tile = wn*4 + nt2;
      s16x8 wfh = *(const s16x8*)(W2h + (size_t)(tile*16 + kt2)*512 + lane*8);
      s16x8 wfl = *(const s16x8*)(W2l + (size_t)(tile*16 + kt2)*512 + lane*8);
      acc2[nt2] = __builtin_amdgcn_mfma_f32_16x16x32_bf16(wfh, hfh, acc2[nt2], 0,0,0);
      acc2[nt2] = __builtin_amdgcn_mfma_f32_16x16x32_bf16(wfh, hfl, acc2[nt2], 0,0,0);
      acc2[nt2] = __builtin_amdgcn_mfma_f32_16x16x32_bf16(wfl, hfh, acc2[nt2], 0,0,0);
    }
  }

  int hrow = wrh*16 + c16;
  size_t grow = row0 + (size_t)hrow;
  const float* xr = x + grow*HID;
  float vals[16];
  float s = 0.f, q = 0.f;
  #pragma unroll
  for (int nt2 = 0; nt2 < 4; ++nt2){
    #pragma unroll
    for (int r = 0; r < 4; ++r){
      int j = (wn*4 + nt2)*16 + g*4 + r;
      float v = acc2[nt2][r] + b2[j] + xr[j];
      vals[nt2*4+r] = v;
      s += v; q += v*v;
    }
  }
  s += __shfl_xor(s, 16, 64);
  s += __shfl_xor(s, 32, 64);
  q += __shfl_xor(q, 16, 64);
  q += __shfl_xor(q, 32, 64);
  if (g == 0){
    red_s[wrh][wn][c16] = s;
    red_q[wrh][wn][c16] = q;
  }
  __syncthreads();
  float s_tot = red_s[wrh][0][c16] + red_s[wrh][1][c16];
  float q_tot = red_q[wrh][0][c16] + red_q[wrh][1][c16];
  float mean = s_tot * (1.f/HID);
  float var = q_tot * (1.f/HID) - mean*mean;
  float rstd = rsqrtf(var + 1e-5f);
  float* orow = x + grow*HID;
  #pragma unroll
  for (int nt2 = 0; nt2 < 4; ++nt2){
    #pragma unroll
    for (int r = 0; r < 4; ++r){
      int j = (wn*4 + nt2)*16 + g*4 + r;
      orow[j] = (vals[nt2*4+r]-mean)*rstd*gam[j] + bet[j];
    }
  }
}

// attention pooling + session vector (proven, unchanged).
__global__ void final_k(const float* __restrict__ x, const float* __restrict__ attW,
                        const float* __restrict__ attb, const float* __restrict__ sessW,
                        const float* __restrict__ sessb, float* __restrict__ sess){
  int b = blockIdx.x; int t = threadIdx.x;
  __shared__ float av[SEQ];
  __shared__ __align__(16) float cat[256];
  const float* xb = x + (size_t)b*SEQ*HID;
  if (t < SEQ){
    float a = attb[0];
    for (int c = 0; c < HID; ++c) a += xb[t*HID + c]*attW[c];
    av[t] = a;
  }
  __syncthreads();
  if (t == 0){
    float s = 0.f;
    for (int l = 0; l < SEQ; ++l) s += av[l];
    float inv = 1.f/s;
    for (int l = 0; l < SEQ; ++l) av[l] *= inv;
  }
  __syncthreads();
  float gacc = 0.f;
  for (int l = 0; l < SEQ; ++l) gacc += xb[l*HID + t]*av[l];
  cat[t] = xb[49*HID + t];
  cat[128+t] = gacc;
  __syncthreads();
  float acc = sessb[t];
  const float4* w = (const float4*)(sessW + (size_t)t*256);
  const float4* c4 = (const float4*)cat;
  #pragma unroll 8
  for (int j = 0; j < 64; ++j){
    float4 wv=w[j]; float4 cv=c4[j];
    acc += wv.x*cv.x + wv.y*cv.y + wv.z*cv.z + wv.w*cv.w;
  }
  sess[(size_t)b*HID + t] = acc;
}

// logits: XCD swizzle + two col-slabs + packed emb frags + LDS/NT stores.
__global__ __launch_bounds__(256) void logits_mfma_k(
    const unsigned short* __restrict__ sessH, const unsigned short* __restrict__ sessL,
    const unsigned short* __restrict__ embH, const unsigned short* __restrict__ embL,
    float* __restrict__ out)
{
  __shared__ unsigned short Sh[32*128];
  __shared__ unsigned short Sl[32*128];
  __shared__ float Ob[32*132];
  int t = threadIdx.x;
  int wave = t >> 6, lane = t & 63;
  int g = lane >> 4, c16 = lane & 15;
  int wrh = wave >> 1;
  int wn  = wave & 1;
  int id = blockIdx.x;             // 0..12799
  int xcd = id & 7;
  int j = id >> 3;
  int dslab = xcd*25 + (j >> 6);   // 0..199
  int rowt = j & 63;
  size_t row0 = (size_t)rowt * 32;

  #pragma unroll
  for (int it = 0; it < 2; ++it){
    int idx8 = it*256 + t;
    int r = idx8 >> 4;
    int c8 = idx8 & 15;
    s16x8 ph = *(const s16x8*)(sessH + (row0 + r)*HID + c8*8);
    s16x8 pl = *(const s16x8*)(sessL + (row0 + r)*HID + c8*8);
    int slot = c8 ^ (r & 15);
    *(s16x8*)((char*)Sh + r*256 + slot*16) = ph;
    *(s16x8*)((char*)Sl + r*256 + slot*16) = pl;
  }
  __syncthreads();

  int rloc = wrh*16 + c16;
  s16x8 afh[4], afl[4];
  #pragma unroll
  for (int kt = 0; kt < 4; ++kt){
    int slot = (kt*4 + g) ^ (rloc & 15);
    afh[kt] = *(const s16x8*)((const char*)Sh + rloc*256 + slot*16);
    afl[kt] = *(const s16x8*)((const char*)Sl + rloc*256 + slot*16);
  }

  #pragma unroll
  for (int ph = 0; ph < 2; ++ph){
    int n0 = dslab*256 + ph*128;
    #pragma unroll
    for (int nt = 0; nt < 4; ++nt){
      int tb = (n0 >> 4) + wn*4 + nt;
      int ncol = n0 + (wn*4 + nt)*16 + c16;
      f32x4 acc = {0.f,0.f,0.f,0.f};
      #pragma unroll
      for (int kt = 0; kt < 4; ++kt){
        s16x8 bh = *(const s16x8*)(embH + (size_t)(tb*4 + kt)*512 + lane*8);
        s16x8 bl = *(const s16x8*)(embL + (size_t)(tb*4 + kt)*512 + lane*8);
        acc = __builtin_amdgcn_mfma_f32_16x16x32_bf16(afh[kt], bh, acc, 0,0,0);
        acc = __builtin_amdgcn_mfma_f32_16x16x32_bf16(afh[kt], bl, acc, 0,0,0);
        acc = __builtin_amdgcn_mfma_f32_16x16x32_bf16(afl[kt], bh, acc, 0,0,0);
      }
      #pragma unroll
      for (int r = 0; r < 4; ++r){
        int m = wrh*16 + g*4 + r;
        Ob[m*132 + (wn*4 + nt)*16 + c16] = acc[r];
      }
    }
    __syncthreads();

    #pragma unroll
    for (int k = 0; k < 16; ++k){
      int idx = k*256 + t;
      int r_ = idx >> 7;
      int c_ = idx & 127;
      int ncol = n0 + c_;
      if (ncol < NOUT){
        __builtin_nontemporal_store(Ob[r_*132 + c_],
                                    out + (row0 + r_)*(size_t)NOUT + ncol);
      }
    }
    __syncthreads();
  }
}

extern "C" void kernel_launch(void* const* d_in, const int* in_sizes, int n_in,
                              void* d_out, int out_size, void* d_ws, size_t ws_size,
                              hipStream_t stream){
  const int*   ids  = (const int*)d_in[0];
  const float* A    = (const float*)d_in[1];
  const float* emb  = (const float*)d_in[2];
  const float* pos  = (const float*)d_in[3];
  const float* mixW = (const float*)d_in[4];
  const float* mixb = (const float*)d_in[5];
  const float* Wq   = (const float*)d_in[6];
  const float* bq   = (const float*)d_in[7];
  const float* Wk   = (const float*)d_in[8];
  const float* bk   = (const float*)d_in[9];
  const float* Wv   = (const float*)d_in[10];
  const float* bv   = (const float*)d_in[11];
  const float* Wo   = (const float*)d_in[12];
  const float* bo   = (const float*)d_in[13];
  const float* ln1g = (const float*)d_in[14];
  const float* ln1b = (const float*)d_in[15];
  const float* W1   = (const float*)d_in[16];
  const float* b1   = (const float*)d_in[17];
  const float* W2   = (const float*)d_in[18];
  const float* b2   = (const float*)d_in[19];
  const float* ln2g = (const float*)d_in[20];
  const float* ln2b = (const float*)d_in[21];
  const float* attW = (const float*)d_in[22];
  const float* attb = (const float*)d_in[23];
  const float* sessW= (const float*)d_in[24];
  const float* sessb= (const float*)d_in[25];
  float* out = (float*)d_out;

  float* xA   = (float*)d_ws;
  float* xB   = xA + (size_t)NROWS*HID;
  float* sess = xB + (size_t)NROWS*HID;
  // FFN hi/lo splits in the sess region (1MB; sess written only by final_k).
  unsigned short* W1h = (unsigned short*)sess;
  unsigned short* W1l = W1h + (size_t)2*INNER*HID;
  unsigned short* W2h = W1l + (size_t)2*INNER*HID;
  unsigned short* W2l = W2h + (size_t)2*INNER*HID;
  // Weight splits in d_out tail.
  unsigned short* awb = (unsigned short*)(out + (size_t)out_size - 131072);
  unsigned short* Wqkvh = awb;
  unsigned short* Wqkvl = awb + 98304;
  unsigned short* Woh   = awb + 196608;
  unsigned short* Wol   = awb + 229376;
  unsigned short* mwb = (unsigned short*)(out + (size_t)out_size - 131072 - 65536);
  unsigned short* mWh = mwb;
  unsigned short* mWl = mwb + 65536;
  // Activation scratch in d_out head (lifetimes pairwise disjoint):
  //   qkvbuf [0, 157.3MB) fp32; xP/oP [157.3, 209.7MB) packed;
  //   xQ [0, 52.4MB) packed (qkvbuf dead); Hp [52.4, 262.1MB) packed.
  float* qkvbuf = out;
  unsigned short* xPh = (unsigned short*)(out + (size_t)NROWS*384);
  unsigned short* xPl = xPh + (size_t)NROWS*HID;
  unsigned short* oPh = xPh;                      // alias: xP dead before attn writes oP
  unsigned short* oPl = xPl;
  unsigned short* xQh = (unsigned short*)out;
  unsigned short* xQl = xQh + (size_t)NROWS*HID;
  unsigned short* Hph = (unsigned short*)out + (size_t)2*NROWS*HID;
  unsigned short* Hpl = Hph + (size_t)NROWS*INNER;
  // logits hi/lo splits in xB (dead after layer-1 mix)
  unsigned short* embHs = (unsigned short*)xB;
  unsigned short* embLs = embHs + (size_t)NPAD3*HID;
  unsigned short* sessH = embLs + (size_t)NPAD3*HID;
  unsigned short* sessL = sessH + (size_t)BSZ*HID;

  cvtw2_k<<<512, 256, 0, stream>>>(W1, W2, W1h, W1l, W2h, W2l);
  cvtw_qkvo_k<<<128, 256, 0, stream>>>(Wq, Wk, Wv, Wo, awb);
  cvtmix_k<<<256, 256, 0, stream>>>(mixW, mWh, mWl);
  embed_k<<<NROWS, HID, 0, stream>>>(ids, emb, pos, xA);
  float* xc = xA; float* xn = xB;
  for (int i = 0; i < 2; ++i){
    mix_mfma_k<<<BSZ, 256, 0, stream>>>(A, xc,
        mWh + (size_t)i*HID*256, mWl + (size_t)i*HID*256, mixb + i*HID, xn,
        xPh, xPl);
    qkv_mfma_k<<<NROWS/64, 256, 0, stream>>>(xPh, xPl,
        Wqkvh + (size_t)i*384*HID, Wqkvl + (size_t)i*384*HID,
        bq + i*HID, bk + i*HID, bv + i*HID, qkvbuf);
    attn_core_k<<<BSZ*NHEAD, 256, 0, stream>>>(qkvbuf, oPh, oPl);
    oproj_mfma_k<<<NROWS/64, 256, 0, stream>>>(oPh, oPl,
        Woh + (size_t)i*HID*HID, Wol + (size_t)i*HID*HID,
        bo + i*HID, ln1g + i*HID, ln1b + i*HID, xn, xQh, xQl);
    ffn1_k<<<NROWS/64, 256, 0, stream>>>(xQh, xQl,
        W1h + (size_t)i*INNER*HID, W1l + (size_t)i*INNER*HID, b1 + i*INNER,
        Hph, Hpl);
    ffn2_k<<<NROWS/32, 256, 0, stream>>>(Hph, Hpl,
        W2h + (size_t)i*INNER*HID, W2l + (size_t)i*INNER*HID, b2 + i*HID,
        ln2g + i*HID, ln2b + i*HID, xn);
    float* tmp = xc; xc = xn; xn = tmp;
  }
  final_k<<<BSZ, HID, 0, stream>>>(xc, attW, attb, sessW, sessb, sess);
  cvt_logits_k<<<NPAD3*HID/256, 256, 0, stream>>>(sess, emb, sessH, sessL, embHs, embLs);
  logits_mfma_k<<<8*25*64, 256, 0, stream>>>(sessH, sessL, embHs, embLs, out);
}

// Round 23
// 1523.296 us; speedup vs baseline: 1.1189x; 1.1189x over previous
//
#include <hip/hip_runtime.h>

#define BSZ 2048
#define SEQ 50
#define HID 128
#define NHEAD 4
#define HDIM 32
#define INNER 512
#define NITEMS 50000
#define NOUT 49999
#define NPAD3 51200

typedef float f32x4 __attribute__((ext_vector_type(4)));
typedef short s16x8 __attribute__((ext_vector_type(8)));

__device__ __forceinline__ unsigned short f2b(float f){
  unsigned int u = __builtin_bit_cast(unsigned int, f);
  u = (u + 0x7FFFu + ((u >> 16) & 1u)) >> 16;
  return (unsigned short)u;
}
__device__ __forceinline__ float b2f(unsigned short h){
  unsigned int u = ((unsigned int)h) << 16;
  return __builtin_bit_cast(float, u);
}
// fragment-major packed offset: (n,k) with K/32 = ksteps.
// lane (g,c16) of frag (tile,kt) reads 8 consecutive ushorts at
// (tile*ksteps+kt)*512 + lane*8  (lane = g*16 + c16).
__device__ __forceinline__ size_t pk(int n, int k, int ksteps){
  return ((size_t)((n >> 4)*ksteps + (k >> 5))*64 + ((k >> 3) & 3)*16 + (n & 15))*8 + (k & 7);
}

__global__ void embed_k(const int* __restrict__ ids, const float* __restrict__ emb,
                        const float* __restrict__ pos, float* __restrict__ x){
  int row = blockIdx.x;          // b*SEQ + l
  int l = row % SEQ;
  int t = threadIdx.x;
  int id = ids[row];
  x[(size_t)row*HID + t] = emb[(size_t)id*HID + t] + pos[l*HID + t];
}

// split W1/W2 into bf16 hi/lo pairs, fragment-major packed.
__global__ void cvtw2_k(const float* __restrict__ W1, const float* __restrict__ W2,
                        unsigned short* __restrict__ W1h, unsigned short* __restrict__ W1l,
                        unsigned short* __restrict__ W2h, unsigned short* __restrict__ W2l){
  int i = blockIdx.x*256 + threadIdx.x;   // 0..131071
  {
    int l = i >> 16, rc = i & 65535;
    int n = rc >> 7, k = rc & 127;          // W1 [512][128]
    float w = W1[i];
    unsigned short h = f2b(w);
    size_t off = (size_t)l*65536 + pk(n, k, 4);
    W1h[off] = h; W1l[off] = f2b(w - b2f(h));
  }
  {
    int l = i >> 16, rc = i & 65535;
    int n = rc >> 9, k = rc & 511;          // W2 [128][512]
    float w = W2[i];
    unsigned short h = f2b(w);
    size_t off = (size_t)l*65536 + pk(n, k, 16);
    W2h[off] = h; W2l[off] = f2b(w - b2f(h));
  }
}

// Wq/Wk/Wv stacked [2][384][128] packed; Wo [2][128][128] packed.
__global__ void cvtw_qkvo_k(const float* __restrict__ Wq, const float* __restrict__ Wk,
                            const float* __restrict__ Wv, const float* __restrict__ Wo,
                            unsigned short* __restrict__ dst){
  int i = blockIdx.x*256 + threadIdx.x;   // 0..32767
  int l = i >> 14;
  int rc = i & 16383;
  int r = rc >> 7, k = rc & 127;
  unsigned short* Wqkvh = dst;
  unsigned short* Wqkvl = dst + 98304;
  unsigned short* Woh   = dst + 196608;
  unsigned short* Wol   = dst + 229376;
  size_t base = (size_t)l*49152;
  float w; unsigned short h;
  w = Wq[i]; h = f2b(w);
  { size_t o = base + pk(r, k, 4);        Wqkvh[o] = h; Wqkvl[o] = f2b(w - b2f(h)); }
  w = Wk[i]; h = f2b(w);
  { size_t o = base + pk(128 + r, k, 4);  Wqkvh[o] = h; Wqkvl[o] = f2b(w - b2f(h)); }
  w = Wv[i]; h = f2b(w);
  { size_t o = base + pk(256 + r, k, 4);  Wqkvh[o] = h; Wqkvl[o] = f2b(w - b2f(h)); }
  w = Wo[i]; h = f2b(w);
  { size_t o = (size_t)l*16384 + pk(r, k, 4); Woh[o] = h; Wol[o] = f2b(w - b2f(h)); }
}

// mixW [2][128][256] -> hi/lo packed (ksteps=8)
__global__ void cvtmix_k(const float* __restrict__ mixW,
                         unsigned short* __restrict__ mWh, unsigned short* __restrict__ mWl){
  int i = blockIdx.x*256 + threadIdx.x;   // 0..65535
  int l = i >> 15, rc = i & 32767;
  int n = rc >> 8, k = rc & 255;
  float w = mixW[i];
  unsigned short h = f2b(w);
  size_t off = (size_t)l*32768 + pk(n, k, 8);
  mWh[off] = h; mWl[off] = f2b(w - b2f(h));
}

// sess plain hi/lo; emb packed hi/lo (zero-padded to NPAD3, ksteps=4).
__global__ void cvt_logits_k(const float* __restrict__ sess, const float* __restrict__ emb,
                             unsigned short* __restrict__ sessH, unsigned short* __restrict__ sessL,
                             unsigned short* __restrict__ embH, unsigned short* __restrict__ embL){
  int i = blockIdx.x*256 + threadIdx.x;   // 0 .. NPAD3*128-1
  int n = i >> 7, k = i & 127;
  float w = (n < NOUT) ? emb[(size_t)(1+n)*HID + k] : 0.f;
  unsigned short h = f2b(w);
  size_t off = pk(n, k, 4);
  embH[off] = h; embL[off] = f2b(w - b2f(h));
  if (i < BSZ*HID){
    float s = sess[i];
    unsigned short hs = f2b(s);
    sessH[i] = hs; sessL[i] = f2b(s - b2f(hs));
  }
}

// mix via MFMA: one block per batch elem (R11 structure; GEMM2 weights packed).
__global__ __launch_bounds__(256) void mix_mfma_k(
    const float* __restrict__ A, const float* __restrict__ x,
    const unsigned short* __restrict__ mWh, const unsigned short* __restrict__ mWl,
    const float* __restrict__ mixb, float* __restrict__ xout)
{
  __shared__ __align__(16) char smem[65536];
  char* xTh = smem;
  char* xTl = smem + 16384;
  char* Ah  = smem + 32768;
  char* Al  = smem + 49152;
  char* Ch  = smem;
  char* Cl  = smem + 32768;

  int t = threadIdx.x;
  int wave = t >> 6, lane = t & 63;
  int g = lane >> 4, c16 = lane & 15;
  int b = blockIdx.x;
  size_t xbase = (size_t)b * SEQ * HID;

  {
    s16x8 z = {0,0,0,0,0,0,0,0};
    #pragma unroll
    for (int it = 0; it < 16; ++it)
      *(s16x8*)(smem + (it*256 + t)*16) = z;
  }
  __syncthreads();

  for (int task = t; task < SEQ*32; task += 256){
    int r = task >> 5, c4 = task & 31;
    float4 v = *(const float4*)(x + xbase + (size_t)r*HID + c4*4);
    float f[4] = {v.x, v.y, v.z, v.w};
    #pragma unroll
    for (int i = 0; i < 4; ++i){
      int d = c4*4 + i;
      unsigned short hi = f2b(f[i]);
      unsigned short lo = f2b(f[i] - b2f(hi));
      int off = d*128 + ((((r >> 3) ^ (d & 7))<<4)) + (r & 7)*2;
      *(unsigned short*)(xTh + off) = hi;
      *(unsigned short*)(xTl + off) = lo;
    }
  }
  {
    int l = t >> 2, q = t & 3;
    if (l < SEQ){
      const float* Ar = A + (size_t)(b*SEQ + l)*100;
      for (int j = q*25; j < q*25 + 25; ++j){
        float av = Ar[j];
        int col = (j < SEQ) ? j : (64 + (j - SEQ));
        unsigned short hi = f2b(av);
        unsigned short lo = f2b(av - b2f(hi));
        int off = l*256 + ((((col >> 3) ^ (l & 15))<<4)) + (col & 7)*2;
        *(unsigned short*)(Ah + off) = hi;
        *(unsigned short*)(Al + off) = lo;
      }
    }
  }
  __syncthreads();

  int rA = wave*16 + c16;
  s16x8 aih[2], ail[2], aoh[2], aol[2];
  #pragma unroll
  for (int kt = 0; kt < 2; ++kt){
    int ci = kt*4 + g;
    int co = 8 + kt*4 + g;
    int offi = rA*256 + ((ci ^ (rA & 15))<<4);
    int offo = rA*256 + ((co ^ (rA & 15))<<4);
    aih[kt] = *(const s16x8*)(Ah + offi);
    ail[kt] = *(const s16x8*)(Al + offi);
    aoh[kt] = *(const s16x8*)(Ah + offo);
    aol[kt] = *(const s16x8*)(Al + offo);
  }
  f32x4 accin[8], accout[8];
  #pragma unroll
  for (int nt = 0; nt < 8; ++nt){ accin[nt] = (f32x4){0,0,0,0}; accout[nt] = (f32x4){0,0,0,0}; }
  #pragma unroll
  for (int kt = 0; kt < 2; ++kt){
    #pragma unroll
    for (int nt = 0; nt < 8; ++nt){
      int d = nt*16 + c16;
      int boff = d*128 + ((((kt*4 + g) ^ (d & 7)))<<4);
      s16x8 bh = *(const s16x8*)(xTh + boff);
      s16x8 bl = *(const s16x8*)(xTl + boff);
      accin[nt]  = __builtin_amdgcn_mfma_f32_16x16x32_bf16(aih[kt], bh, accin[nt], 0,0,0);
      accin[nt]  = __builtin_amdgcn_mfma_f32_16x16x32_bf16(aih[kt], bl, accin[nt], 0,0,0);
      accin[nt]  = __builtin_amdgcn_mfma_f32_16x16x32_bf16(ail[kt], bh, accin[nt], 0,0,0);
      accout[nt] = __builtin_amdgcn_mfma_f32_16x16x32_bf16(aoh[kt], bh, accout[nt], 0,0,0);
      accout[nt] = __builtin_amdgcn_mfma_f32_16x16x32_bf16(aoh[kt], bl, accout[nt], 0,0,0);
      accout[nt] = __builtin_amdgcn_mfma_f32_16x16x32_bf16(aol[kt], bh, accout[nt], 0,0,0);
    }
  }
  __syncthreads();

  #pragma unroll
  for (int nt = 0; nt < 8; ++nt){
    #pragma unroll
    for (int r = 0; r < 4; ++r){
      int l = wave*16 + g*4 + r;
      int ci_ = nt*16 + c16;
      float vi = accin[nt][r];
      unsigned short hi = f2b(vi);
      int offi = l*512 + (((ci_ >> 3) ^ (l & 15))<<4) + (ci_ & 7)*2;
      *(unsigned short*)(Ch + offi) = hi;
      *(unsigned short*)(Cl + offi) = f2b(vi - b2f(hi));
      int co_ = 128 + nt*16 + c16;
      float vo = accout[nt][r];
      unsigned short ho = f2b(vo);
      int offo = l*512 + (((co_ >> 3) ^ (l & 15))<<4) + (co_ & 7)*2;
      *(unsigned short*)(Ch + offo) = ho;
      *(unsigned short*)(Cl + offo) = f2b(vo - b2f(ho));
    }
  }
  __syncthreads();

  int rc = wave*16 + c16;
  f32x4 acc2[8];
  #pragma unroll
  for (int nt = 0; nt < 8; ++nt) acc2[nt] = (f32x4){0,0,0,0};
  for (int kt2 = 0; kt2 < 8; ++kt2){
    int slot = (kt2*4 + g) ^ (rc & 15);
    s16x8 cfh = *(const s16x8*)(Ch + rc*512 + slot*16);
    s16x8 cfl = *(const s16x8*)(Cl + rc*512 + slot*16);
    #pragma unroll
    for (int nt = 0; nt < 8; ++nt){
      s16x8 wh = *(const s16x8*)(mWh + (size_t)(nt*8 + kt2)*512 + lane*8);
      s16x8 wl = *(const s16x8*)(mWl + (size_t)(nt*8 + kt2)*512 + lane*8);
      acc2[nt] = __builtin_amdgcn_mfma_f32_16x16x32_bf16(cfh, wh, acc2[nt], 0,0,0);
      acc2[nt] = __builtin_amdgcn_mfma_f32_16x16x32_bf16(cfh, wl, acc2[nt], 0,0,0);
      acc2[nt] = __builtin_amdgcn_mfma_f32_16x16x32_bf16(cfl, wh, acc2[nt], 0,0,0);
    }
  }
  #pragma unroll
  for (int nt = 0; nt < 8; ++nt){
    int j = nt*16 + c16;
    float bb = mixb[j];
    #pragma unroll
    for (int r = 0; r < 4; ++r){
      int l = wave*16 + g*4 + r;
      if (l < SEQ) xout[xbase + (size_t)l*HID + j] = acc2[nt][r] + bb;
    }
  }
}

// QKV projection: 64 rows/block, packed weight frags (proven R20).
__global__ __launch_bounds__(256) void qkv_mfma_k(
    const float* __restrict__ x,
    const unsigned short* __restrict__ Wh, const unsigned short* __restrict__ Wl,
    const float* __restrict__ bq, const float* __restrict__ bk,
    const float* __restrict__ bv, float* __restrict__ qkv)
{
  __shared__ unsigned short Xh[64*128];
  __shared__ unsigned short Xl[64*128];
  int t = threadIdx.x;
  int wave = t >> 6, lane = t & 63;
  int g = lane >> 4, c16 = lane & 15;
  int wrh = wave >> 1;
  int wn  = wave & 1;
  size_t row0 = (size_t)blockIdx.x * 64;

  #pragma unroll
  for (int it = 0; it < 4; ++it){
    int idx8 = it*256 + t;
    int r = idx8 >> 4;
    int c8 = idx8 & 15;
    const float* src = x + (row0 + r)*HID + c8*8;
    float4 v0 = *(const float4*)(src);
    float4 v1 = *(const float4*)(src + 4);
    float f[8] = {v0.x,v0.y,v0.z,v0.w,v1.x,v1.y,v1.z,v1.w};
    s16x8 ph, pl;
    #pragma unroll
    for (int e = 0; e < 8; ++e){
      unsigned short hi = f2b(f[e]);
      ph[e] = (short)hi;
      pl[e] = (short)f2b(f[e] - b2f(hi));
    }
    int slot = c8 ^ (r & 15);
    *(s16x8*)((char*)Xh + r*256 + slot*16) = ph;
    *(s16x8*)((char*)Xl + r*256 + slot*16) = pl;
  }
  __syncthreads();

  int rl0 = wrh*16 + c16;
  int rl1 = 32 + rl0;
  s16x8 a0h[4], a0l[4], a1h[4], a1l[4];
  #pragma unroll
  for (int kt = 0; kt < 4; ++kt){
    int slot = (kt*4 + g) ^ (rl0 & 15);
    a0h[kt] = *(const s16x8*)((const char*)Xh + rl0*256 + slot*16);
    a0l[kt] = *(const s16x8*)((const char*)Xl + rl0*256 + slot*16);
    a1h[kt] = *(const s16x8*)((const char*)Xh + rl1*256 + slot*16);
    a1l[kt] = *(const s16x8*)((const char*)Xl + rl1*256 + slot*16);
  }

  for (int nt = 0; nt < 12; ++nt){
    int tile = wn*12 + nt;
    int ncol = tile*16 + c16;          // 0..383
    f32x4 acc0 = {0.f,0.f,0.f,0.f};
    f32x4 acc1 = {0.f,0.f,0.f,0.f};
    #pragma unroll
    for (int kt = 0; kt < 4; ++kt){
      s16x8 bh = *(const s16x8*)(Wh + (size_t)(tile*4 + kt)*512 + lane*8);
      s16x8 bl = *(const s16x8*)(Wl + (size_t)(tile*4 + kt)*512 + lane*8);
      acc0 = __builtin_amdgcn_mfma_f32_16x16x32_bf16(a0h[kt], bh, acc0, 0,0,0);
      acc0 = __builtin_amdgcn_mfma_f32_16x16x32_bf16(a0h[kt], bl, acc0, 0,0,0);
      acc0 = __builtin_amdgcn_mfma_f32_16x16x32_bf16(a0l[kt], bh, acc0, 0,0,0);
      acc1 = __builtin_amdgcn_mfma_f32_16x16x32_bf16(a1h[kt], bh, acc1, 0,0,0);
      acc1 = __builtin_amdgcn_mfma_f32_16x16x32_bf16(a1h[kt], bl, acc1, 0,0,0);
      acc1 = __builtin_amdgcn_mfma_f32_16x16x32_bf16(a1l[kt], bh, acc1, 0,0,0);
    }
    int mat = ncol >> 7;
    int colin = ncol & 127;
    float bias = (mat == 0) ? bq[colin] : (mat == 1 ? bk[colin] : bv[colin]);
    #pragma unroll
    for (int r = 0; r < 4; ++r){
      int m = wrh*16 + g*4 + r;
      qkv[(row0 + m)*384 + ncol] = acc0[r] + bias;
      qkv[(row0 + 32 + m)*384 + ncol] = acc1[r] + bias;
    }
  }
}

// Attention core (proven VALU structure, unchanged).
__global__ void attn_core_k(const float* __restrict__ qkv, float* __restrict__ o){
  int blk = blockIdx.x; int b = blk / NHEAD; int h = blk % NHEAD;
  int t = threadIdx.x;
  __shared__ float qs[SEQ][HDIM];
  __shared__ float ks[SEQ][HDIM];
  __shared__ float vs[SEQ][HDIM];
  __shared__ float ss[SEQ][SEQ+2];
  size_t base = (size_t)b*SEQ*384 + h*HDIM;
  for (int task = t; task < SEQ*HDIM; task += 256){
    int l = task >> 5, d = task & 31;
    const float* p = qkv + base + (size_t)l*384 + d;
    qs[l][d] = p[0];
    ks[l][d] = p[128];
    vs[l][d] = p[256];
  }
  __syncthreads();
  for (int task = t; task < SEQ*SEQ; task += 256){
    int l = task / SEQ, m = task % SEQ;
    float a = 0.f;
    #pragma unroll
    for (int d = 0; d < HDIM; ++d) a += qs[l][d]*ks[m][d];
    ss[l][m] = a * 0.17677669529663687f;  // 1/sqrt(32)
  }
  __syncthreads();
  if (t < SEQ){
    float mx = -1e30f;
    for (int m = 0; m < SEQ; ++m) mx = fmaxf(mx, ss[t][m]);
    float sum = 0.f;
    for (int m = 0; m < SEQ; ++m){ float e = __expf(ss[t][m]-mx); ss[t][m]=e; sum+=e; }
    float inv = 1.f/sum;
    for (int m = 0; m < SEQ; ++m) ss[t][m] *= inv;
  }
  __syncthreads();
  for (int task = t; task < SEQ*HDIM; task += 256){
    int l = task >> 5, d = task & 31;
    float a = 0.f;
    for (int m = 0; m < SEQ; ++m) a += ss[l][m]*vs[m][d];
    o[((size_t)b*SEQ+l)*HID + h*HDIM + d] = a;
  }
}

// O @ Wo^T + bo + residual + LN1: 64 rows/block, packed Wo frags (proven R20).
__global__ __launch_bounds__(256) void oproj_mfma_k(
    const float* __restrict__ o,
    const unsigned short* __restrict__ Woh_, const unsigned short* __restrict__ Wol_,
    const float* __restrict__ bo, const float* __restrict__ g1,
    const float* __restrict__ be1, float* x)
{
  __shared__ unsigned short Oh[64*128];
  __shared__ unsigned short Ol[64*128];
  __shared__ float red_s[2][2][2][16];
  __shared__ float red_q[2][2][2][16];
  int t = threadIdx.x;
  int wave = t >> 6, lane = t & 63;
  int g = lane >> 4, c16 = lane & 15;
  int wrh = wave >> 1;
  int wn  = wave & 1;
  size_t row0 = (size_t)blockIdx.x * 64;

  #pragma unroll
  for (int it = 0; it < 4; ++it){
    int idx8 = it*256 + t;
    int r = idx8 >> 4;
    int c8 = idx8 & 15;
    const float* src = o + (row0 + r)*HID + c8*8;
    float4 v0 = *(const float4*)(src);
    float4 v1 = *(const float4*)(src + 4);
    float f[8] = {v0.x,v0.y,v0.z,v0.w,v1.x,v1.y,v1.z,v1.w};
    s16x8 ph, pl;
    #pragma unroll
    for (int e = 0; e < 8; ++e){
      unsigned short hi = f2b(f[e]);
      ph[e] = (short)hi;
      pl[e] = (short)f2b(f[e] - b2f(hi));
    }
    int slot = c8 ^ (r & 15);
    *(s16x8*)((char*)Oh + r*256 + slot*16) = ph;
    *(s16x8*)((char*)Ol + r*256 + slot*16) = pl;
  }
  __syncthreads();

  int rl0 = wrh*16 + c16;
  int rl1 = 32 + rl0;
  s16x8 a0h[4], a0l[4], a1h[4], a1l[4];
  #pragma unroll
  for (int kt = 0; kt < 4; ++kt){
    int slot = (kt*4 + g) ^ (rl0 & 15);
    a0h[kt] = *(const s16x8*)((const char*)Oh + rl0*256 + slot*16);
    a0l[kt] = *(const s16x8*)((const char*)Ol + rl0*256 + slot*16);
    a1h[kt] = *(const s16x8*)((const char*)Oh + rl1*256 + slot*16);
    a1l[kt] = *(const s16x8*)((const char*)Ol + rl1*256 + slot*16);
  }

  float vals[2][4][4];
  #pragma unroll
  for (int nt = 0; nt < 4; ++nt){
    int tile = wn*4 + nt;
    int jcol = tile*16 + c16;
    f32x4 acc0 = {0.f,0.f,0.f,0.f};
    f32x4 acc1 = {0.f,0.f,0.f,0.f};
    #pragma unroll
    for (int kt = 0; kt < 4; ++kt){
      s16x8 bh = *(const s16x8*)(Woh_ + (size_t)(tile*4 + kt)*512 + lane*8);
      s16x8 bl = *(const s16x8*)(Wol_ + (size_t)(tile*4 + kt)*512 + lane*8);
      acc0 = __builtin_amdgcn_mfma_f32_16x16x32_bf16(a0h[kt], bh, acc0, 0,0,0);
      acc0 = __builtin_amdgcn_mfma_f32_16x16x32_bf16(a0h[kt], bl, acc0, 0,0,0);
      acc0 = __builtin_amdgcn_mfma_f32_16x16x32_bf16(a0l[kt], bh, acc0, 0,0,0);
      acc1 = __builtin_amdgcn_mfma_f32_16x16x32_bf16(a1h[kt], bh, acc1, 0,0,0);
      acc1 = __builtin_amdgcn_mfma_f32_16x16x32_bf16(a1h[kt], bl, acc1, 0,0,0);
      acc1 = __builtin_amdgcn_mfma_f32_16x16x32_bf16(a1l[kt], bh, acc1, 0,0,0);
    }
    float bias = bo[jcol];
    #pragma unroll
    for (int r = 0; r < 4; ++r){
      int m = wrh*16 + g*4 + r;
      vals[0][nt][r] = acc0[r] + bias + x[(row0 + m)*HID + jcol];
      vals[1][nt][r] = acc1[r] + bias + x[(row0 + 32 + m)*HID + jcol];
    }
  }

  #pragma unroll
  for (int q_ = 0; q_ < 2; ++q_){
    #pragma unroll
    for (int r = 0; r < 4; ++r){
      float s_ = vals[q_][0][r] + vals[q_][1][r] + vals[q_][2][r] + vals[q_][3][r];
      float qq = vals[q_][0][r]*vals[q_][0][r] + vals[q_][1][r]*vals[q_][1][r]
               + vals[q_][2][r]*vals[q_][2][r] + vals[q_][3][r]*vals[q_][3][r];
      s_ += __shfl_xor(s_, 1, 64); qq += __shfl_xor(qq, 1, 64);
      s_ += __shfl_xor(s_, 2, 64); qq += __shfl_xor(qq, 2, 64);
      s_ += __shfl_xor(s_, 4, 64); qq += __shfl_xor(qq, 4, 64);
      s_ += __shfl_xor(s_, 8, 64); qq += __shfl_xor(qq, 8, 64);
      if (c16 == 0){
        red_s[q_][wrh][wn][g*4 + r] = s_;
        red_q[q_][wrh][wn][g*4 + r] = qq;
      }
    }
  }
  __syncthreads();
  #pragma unroll
  for (int q_ = 0; q_ < 2; ++q_){
    #pragma unroll
    for (int r = 0; r < 4; ++r){
      int m = wrh*16 + g*4 + r;
      float s_tot = red_s[q_][wrh][0][g*4 + r] + red_s[q_][wrh][1][g*4 + r];
      float q_tot = red_q[q_][wrh][0][g*4 + r] + red_q[q_][wrh][1][g*4 + r];
      float mean = s_tot * (1.f/HID);
      float var = q_tot * (1.f/HID) - mean*mean;
      float rstd = rsqrtf(var + 1e-5f);
      #pragma unroll
      for (int nt = 0; nt < 4; ++nt){
        int jcol = (wn*4 + nt)*16 + c16;
        x[(row0 + q_*32 + m)*HID + jcol] = (vals[q_][nt][r]-mean)*rstd*g1[jcol] + be1[jcol];
      }
    }
  }
}

// FFN part 1: 64 rows/block, packed W1 frags; H written as PACKED bf16 hi/lo
// (fragment-major, ksteps=16) so ffn2 loads B-frags coalesced from global.
__global__ __launch_bounds__(256) void ffn1_k(
    const float* __restrict__ x,
    const unsigned short* __restrict__ W1h, const unsigned short* __restrict__ W1l,
    const float* __restrict__ b1,
    unsigned short* __restrict__ Hph, unsigned short* __restrict__ Hpl)
{
  __shared__ unsigned short Xh[64*128];
  __shared__ unsigned short Xl[64*128];
  int t = threadIdx.x;
  int wave = t >> 6, lane = t & 63;
  int g = lane >> 4, c16 = lane & 15;
  int wrh = wave >> 1;
  int wn  = wave & 1;
  size_t row0 = (size_t)blockIdx.x * 64;

  #pragma unroll
  for (int it = 0; it < 4; ++it){
    int idx8 = it*256 + t;
    int r = idx8 >> 4;
    int c8 = idx8 & 15;
    const float* src = x + (row0 + r)*HID + c8*8;
    float4 v0 = *(const float4*)(src);
    float4 v1 = *(const float4*)(src + 4);
    float f[8] = {v0.x,v0.y,v0.z,v0.w,v1.x,v1.y,v1.z,v1.w};
    s16x8 ph, pl;
    #pragma unroll
    for (int e = 0; e < 8; ++e){
      unsigned short hi = f2b(f[e]);
      ph[e] = (short)hi;
      pl[e] = (short)f2b(f[e] - b2f(hi));
    }
    int slot = c8 ^ (r & 15);
    *(s16x8*)((char*)Xh + r*256 + slot*16) = ph;
    *(s16x8*)((char*)Xl + r*256 + slot*16) = pl;
  }
  __syncthreads();

  int rl0 = wrh*16 + c16;
  int rl1 = 32 + rl0;
  s16x8 a0h[4], a0l[4], a1h[4], a1l[4];
  #pragma unroll
  for (int kt = 0; kt < 4; ++kt){
    int slot = (kt*4 + g) ^ (rl0 & 15);
    a0h[kt] = *(const s16x8*)((const char*)Xh + rl0*256 + slot*16);
    a0l[kt] = *(const s16x8*)((const char*)Xl + rl0*256 + slot*16);
    a1h[kt] = *(const s16x8*)((const char*)Xh + rl1*256 + slot*16);
    a1l[kt] = *(const s16x8*)((const char*)Xl + rl1*256 + slot*16);
  }

  for (int nt = 0; nt < 16; ++nt){
    int tile = wn*16 + nt;
    int ncol = tile*16 + c16;
    f32x4 acc0 = {0.f,0.f,0.f,0.f};
    f32x4 acc1 = {0.f,0.f,0.f,0.f};
    #pragma unroll
    for (int kt = 0; kt < 4; ++kt){
      s16x8 bh = *(const s16x8*)(W1h + (size_t)(tile*4 + kt)*512 + lane*8);
      s16x8 bl = *(const s16x8*)(W1l + (size_t)(tile*4 + kt)*512 + lane*8);
      acc0 = __builtin_amdgcn_mfma_f32_16x16x32_bf16(a0h[kt], bh, acc0, 0,0,0);
      acc0 = __builtin_amdgcn_mfma_f32_16x16x32_bf16(a0h[kt], bl, acc0, 0,0,0);
      acc0 = __builtin_amdgcn_mfma_f32_16x16x32_bf16(a0l[kt], bh, acc0, 0,0,0);
      acc1 = __builtin_amdgcn_mfma_f32_16x16x32_bf16(a1h[kt], bh, acc1, 0,0,0);
      acc1 = __builtin_amdgcn_mfma_f32_16x16x32_bf16(a1h[kt], bl, acc1, 0,0,0);
      acc1 = __builtin_amdgcn_mfma_f32_16x16x32_bf16(a1l[kt], bh, acc1, 0,0,0);
    }
    float bias = b1[ncol];
    #pragma unroll
    for (int r = 0; r < 4; ++r){
      int m0 = (int)row0 + wrh*16 + g*4 + r;
      float h0 = fmaxf(acc0[r] + bias, 0.f);
      unsigned short hh0 = f2b(h0);
      size_t o0 = pk(m0, ncol, 16);
      Hph[o0] = hh0; Hpl[o0] = f2b(h0 - b2f(hh0));
      float h1 = fmaxf(acc1[r] + bias, 0.f);
      unsigned short hh1 = f2b(h1);
      size_t o1 = pk(m0 + 32, ncol, 16);
      Hph[o1] = hh1; Hpl[o1] = f2b(h1 - b2f(hh1));
    }
  }
}

// FFN part 2: H read as packed bf16 hi/lo frags DIRECT from global (no LDS
// staging, no staging barrier); W2 packed frags. LN epilogue unchanged.
__global__ __launch_bounds__(256) void ffn2_k(
    const unsigned short* __restrict__ Hph, const unsigned short* __restrict__ Hpl,
    const unsigned short* __restrict__ W2h, const unsigned short* __restrict__ W2l,
    const float* __restrict__ b2, const float* __restrict__ gam,
    const float* __restrict__ bet, float* x)
{
  __shared__ float red_s[2][2][16];
  __shared__ float red_q[2][2][16];
  int t = threadIdx.x;
  int wave = t >> 6, lane = t & 63;
  int g = lane >> 4, c16 = lane & 15;
  int wrh = wave >> 1;
  int wn  = wave & 1;
  size_t row0 = (size_t)blockIdx.x * 32;
  int rt = (int)(row0 >> 4) + wrh;     // global 16-row tile of H

  f32x4 acc2[4];
  #pragma unroll
  for (int i = 0; i < 4; ++i) acc2[i] = (f32x4){0.f,0.f,0.f,0.f};
  for (int kt2 = 0; kt2 < 16; ++kt2){
    s16x8 hfh = *(const s16x8*)(Hph + (size_t)(rt*16 + kt2)*512 + lane*8);
    s16x8 hfl = *(const s16x8*)(Hpl + (size_t)(rt*16 + kt2)*512 + lane*8);
    #pragma unroll
    for (int nt2 = 0; nt2 < 4; ++nt2){
      int tile = wn*4 + nt2;
      s16x8 wfh = *(const s16x8*)(W2h + (size_t)(tile*16 + kt2)*512 + lane*8);
      s16x8 wfl = *(const s16x8*)(W2l + (size_t)(tile*16 + kt2)*512 + lane*8);
      acc2[nt2] = __builtin_amdgcn_mfma_f32_16x16x32_bf16(wfh, hfh, acc2[nt2], 0,0,0);
      acc2[nt2] = __builtin_amdgcn_mfma_f32_16x16x32_bf16(wfh, hfl, acc2[nt2], 0,0,0);
      acc2[nt2] = __builtin_amdgcn_mfma_f32_16x16x32_bf16(wfl, hfh, acc2[nt2], 0,0,0);
    }
  }

  int hrow = wrh*16 + c16;
  size_t grow = row0 + (size_t)hrow;
  const float* xr = x + grow*HID;
  float vals[16];
  float s = 0.f, q = 0.f;
  #pragma unroll
  for (int nt2 = 0; nt2 < 4; ++nt2){
    #pragma unroll
    for (int r = 0; r < 4; ++r){
      int j = (wn*4 + nt2)*16 + g*4 + r;
      float v = acc2[nt2][r] + b2[j] + xr[j];
      vals[nt2*4+r] = v;
      s += v; q += v*v;
    }
  }
  s += __shfl_xor(s, 16, 64);
  s += __shfl_xor(s, 32, 64);
  q += __shfl_xor(q, 16, 64);
  q += __shfl_xor(q, 32, 64);
  if (g == 0){
    red_s[wrh][wn][c16] = s;
    red_q[wrh][wn][c16] = q;
  }
  __syncthreads();
  float s_tot = red_s[wrh][0][c16] + red_s[wrh][1][c16];
  float q_tot = red_q[wrh][0][c16] + red_q[wrh][1][c16];
  float mean = s_tot * (1.f/HID);
  float var = q_tot * (1.f/HID) - mean*mean;
  float rstd = rsqrtf(var + 1e-5f);
  float* orow = x + grow*HID;
  #pragma unroll
  for (int nt2 = 0; nt2 < 4; ++nt2){
    #pragma unroll
    for (int r = 0; r < 4; ++r){
      int j = (wn*4 + nt2)*16 + g*4 + r;
      orow[j] = (vals[nt2*4+r]-mean)*rstd*gam[j] + bet[j];
    }
  }
}

// attention pooling + session vector (proven, unchanged).
__global__ void final_k(const float* __restrict__ x, const float* __restrict__ attW,
                        const float* __restrict__ attb, const float* __restrict__ sessW,
                        const float* __restrict__ sessb, float* __restrict__ sess){
  int b = blockIdx.x; int t = threadIdx.x;
  __shared__ float av[SEQ];
  __shared__ __align__(16) float cat[256];
  const float* xb = x + (size_t)b*SEQ*HID;
  if (t < SEQ){
    float a = attb[0];
    for (int c = 0; c < HID; ++c) a += xb[t*HID + c]*attW[c];
    av[t] = a;
  }
  __syncthreads();
  if (t == 0){
    float s = 0.f;
    for (int l = 0; l < SEQ; ++l) s += av[l];
    float inv = 1.f/s;
    for (int l = 0; l < SEQ; ++l) av[l] *= inv;
  }
  __syncthreads();
  float gacc = 0.f;
  for (int l = 0; l < SEQ; ++l) gacc += xb[l*HID + t]*av[l];
  cat[t] = xb[49*HID + t];
  cat[128+t] = gacc;
  __syncthreads();
  float acc = sessb[t];
  const float4* w = (const float4*)(sessW + (size_t)t*256);
  const float4* c4 = (const float4*)cat;
  #pragma unroll 8
  for (int j = 0; j < 64; ++j){
    float4 wv=w[j]; float4 cv=c4[j];
    acc += wv.x*cv.x + wv.y*cv.y + wv.z*cv.z + wv.w*cv.w;
  }
  sess[(size_t)b*HID + t] = acc;
}

// logits: XCD swizzle + two col-slabs + packed emb frags + LDS/NT stores.
__global__ __launch_bounds__(256) void logits_mfma_k(
    const unsigned short* __restrict__ sessH, const unsigned short* __restrict__ sessL,
    const unsigned short* __restrict__ embH, const unsigned short* __restrict__ embL,
    float* __restrict__ out)
{
  __shared__ unsigned short Sh[32*128];
  __shared__ unsigned short Sl[32*128];
  __shared__ float Ob[32*132];
  int t = threadIdx.x;
  int wave = t >> 6, lane = t & 63;
  int g = lane >> 4, c16 = lane & 15;
  int wrh = wave >> 1;
  int wn  = wave & 1;
  int id = blockIdx.x;             // 0..12799
  int xcd = id & 7;
  int j = id >> 3;
  int dslab = xcd*25 + (j >> 6);   // 0..199
  int rowt = j & 63;
  size_t row0 = (size_t)rowt * 32;

  #pragma unroll
  for (int it = 0; it < 2; ++it){
    int idx8 = it*256 + t;
    int r = idx8 >> 4;
    int c8 = idx8 & 15;
    s16x8 ph = *(const s16x8*)(sessH + (row0 + r)*HID + c8*8);
    s16x8 pl = *(const s16x8*)(sessL + (row0 + r)*HID + c8*8);
    int slot = c8 ^ (r & 15);
    *(s16x8*)((char*)Sh + r*256 + slot*16) = ph;
    *(s16x8*)((char*)Sl + r*256 + slot*16) = pl;
  }
  __syncthreads();

  int rloc = wrh*16 + c16;
  s16x8 afh[4], afl[4];
  #pragma unroll
  for (int kt = 0; kt < 4; ++kt){
    int slot = (kt*4 + g) ^ (rloc & 15);
    afh[kt] = *(const s16x8*)((const char*)Sh + rloc*256 + slot*16);
    afl[kt] = *(const s16x8*)((const char*)Sl + rloc*256 + slot*16);
  }

  #pragma unroll
  for (int ph = 0; ph < 2; ++ph){
    int n0 = dslab*256 + ph*128;
    #pragma unroll
    for (int nt = 0; nt < 4; ++nt){
      int tb = (n0 >> 4) + wn*4 + nt;
      int ncol = n0 + (wn*4 + nt)*16 + c16;
      f32x4 acc = {0.f,0.f,0.f,0.f};
      #pragma unroll
      for (int kt = 0; kt < 4; ++kt){
        s16x8 bh = *(const s16x8*)(embH + (size_t)(tb*4 + kt)*512 + lane*8);
        s16x8 bl = *(const s16x8*)(embL + (size_t)(tb*4 + kt)*512 + lane*8);
        acc = __builtin_amdgcn_mfma_f32_16x16x32_bf16(afh[kt], bh, acc, 0,0,0);
        acc = __builtin_amdgcn_mfma_f32_16x16x32_bf16(afh[kt], bl, acc, 0,0,0);
        acc = __builtin_amdgcn_mfma_f32_16x16x32_bf16(afl[kt], bh, acc, 0,0,0);
      }
      #pragma unroll
      for (int r = 0; r < 4; ++r){
        int m = wrh*16 + g*4 + r;
        Ob[m*132 + (wn*4 + nt)*16 + c16] = acc[r];
      }
    }
    __syncthreads();

    #pragma unroll
    for (int k = 0; k < 16; ++k){
      int idx = k*256 + t;
      int r_ = idx >> 7;
      int c_ = idx & 127;
      int ncol = n0 + c_;
      if (ncol < NOUT){
        __builtin_nontemporal_store(Ob[r_*132 + c_],
                                    out + (row0 + r_)*(size_t)NOUT + ncol);
      }
    }
    __syncthreads();
  }
}

extern "C" void kernel_launch(void* const* d_in, const int* in_sizes, int n_in,
                              void* d_out, int out_size, void* d_ws, size_t ws_size,
                              hipStream_t stream){
  const int*   ids  = (const int*)d_in[0];
  const float* A    = (const float*)d_in[1];
  const float* emb  = (const float*)d_in[2];
  const float* pos  = (const float*)d_in[3];
  const float* mixW = (const float*)d_in[4];
  const float* mixb = (const float*)d_in[5];
  const float* Wq   = (const float*)d_in[6];
  const float* bq   = (const float*)d_in[7];
  const float* Wk   = (const float*)d_in[8];
  const float* bk   = (const float*)d_in[9];
  const float* Wv   = (const float*)d_in[10];
  const float* bv   = (const float*)d_in[11];
  const float* Wo   = (const float*)d_in[12];
  const float* bo   = (const float*)d_in[13];
  const float* ln1g = (const float*)d_in[14];
  const float* ln1b = (const float*)d_in[15];
  const float* W1   = (const float*)d_in[16];
  const float* b1   = (const float*)d_in[17];
  const float* W2   = (const float*)d_in[18];
  const float* b2   = (const float*)d_in[19];
  const float* ln2g = (const float*)d_in[20];
  const float* ln2b = (const float*)d_in[21];
  const float* attW = (const float*)d_in[22];
  const float* attb = (const float*)d_in[23];
  const float* sessW= (const float*)d_in[24];
  const float* sessb= (const float*)d_in[25];
  float* out = (float*)d_out;

  float* xA   = (float*)d_ws;
  float* xB   = xA + (size_t)BSZ*SEQ*HID;
  float* sess = xB + (size_t)BSZ*SEQ*HID;
  // FFN hi/lo splits in the sess region (1MB; sess written only by final_k).
  unsigned short* W1h = (unsigned short*)sess;
  unsigned short* W1l = W1h + (size_t)2*INNER*HID;
  unsigned short* W2h = W1l + (size_t)2*INNER*HID;
  unsigned short* W2l = W2h + (size_t)2*INNER*HID;
  // Weight splits in d_out tail; qkv/o/H scratch at d_out head.
  unsigned short* awb = (unsigned short*)(out + (size_t)out_size - 131072);
  unsigned short* Wqkvh = awb;
  unsigned short* Wqkvl = awb + 98304;
  unsigned short* Woh   = awb + 196608;
  unsigned short* Wol   = awb + 229376;
  unsigned short* mwb = (unsigned short*)(out + (size_t)out_size - 131072 - 65536);
  unsigned short* mWh = mwb;
  unsigned short* mWl = mwb + 65536;
  float* qkvbuf = out;                               // 102400*384 floats
  float* obuf   = out + (size_t)102400*384;          // 102400*128 floats
  unsigned short* Hph = (unsigned short*)out;        // 102400*512 ushorts (qkv/o dead)
  unsigned short* Hpl = Hph + (size_t)102400*INNER;  // + 102400*512 ushorts = 210MB total
  // logits hi/lo splits in xB (dead after layer-1 mix)
  unsigned short* embHs = (unsigned short*)xB;
  unsigned short* embLs = embHs + (size_t)NPAD3*HID;
  unsigned short* sessH = embLs + (size_t)NPAD3*HID;
  unsigned short* sessL = sessH + (size_t)BSZ*HID;

  cvtw2_k<<<512, 256, 0, stream>>>(W1, W2, W1h, W1l, W2h, W2l);
  cvtw_qkvo_k<<<128, 256, 0, stream>>>(Wq, Wk, Wv, Wo, awb);
  cvtmix_k<<<256, 256, 0, stream>>>(mixW, mWh, mWl);
  embed_k<<<BSZ*SEQ, HID, 0, stream>>>(ids, emb, pos, xA);
  float* xc = xA; float* xn = xB;
  for (int i = 0; i < 2; ++i){
    mix_mfma_k<<<BSZ, 256, 0, stream>>>(A, xc,
        mWh + (size_t)i*HID*256, mWl + (size_t)i*HID*256, mixb + i*HID, xn);
    qkv_mfma_k<<<BSZ*SEQ/64, 256, 0, stream>>>(xn,
        Wqkvh + (size_t)i*384*HID, Wqkvl + (size_t)i*384*HID,
        bq + i*HID, bk + i*HID, bv + i*HID, qkvbuf);
    attn_core_k<<<BSZ*NHEAD, 256, 0, stream>>>(qkvbuf, obuf);
    oproj_mfma_k<<<BSZ*SEQ/64, 256, 0, stream>>>(obuf,
        Woh + (size_t)i*HID*HID, Wol + (size_t)i*HID*HID,
        bo + i*HID, ln1g + i*HID, ln1b + i*HID, xn);
    ffn1_k<<<BSZ*SEQ/64, 256, 0, stream>>>(xn,
        W1h + (size_t)i*INNER*HID, W1l + (size_t)i*INNER*HID, b1 + i*INNER,
        Hph, Hpl);
    ffn2_k<<<BSZ*SEQ/32, 256, 0, stream>>>(Hph, Hpl,
        W2h + (size_t)i*INNER*HID, W2l + (size_t)i*INNER*HID, b2 + i*HID,
        ln2g + i*HID, ln2b + i*HID, xn);
    float* tmp = xc; xc = xn; xn = tmp;
  }
  final_k<<<BSZ, HID, 0, stream>>>(xc, attW, attb, sessW, sessb, sess);
  cvt_logits_k<<<NPAD3*HID/256, 256, 0, stream>>>(sess, emb, sessH, sessL, embHs, embLs);
  logits_mfma_k<<<8*25*64, 256, 0, stream>>>(sessH, sessL, embHs, embLs, out);
}

// Round 24
// 1434.166 us; speedup vs baseline: 1.1884x; 1.0621x over previous
//
#include <hip/hip_runtime.h>

#define BSZ 2048
#define SEQ 50
#define HID 128
#define NHEAD 4
#define HDIM 32
#define INNER 512
#define NITEMS 50000
#define NOUT 49999
#define NPAD3 51200

typedef float f32x4 __attribute__((ext_vector_type(4)));
typedef short s16x8 __attribute__((ext_vector_type(8)));

__device__ __forceinline__ unsigned short f2b(float f){
  unsigned int u = __builtin_bit_cast(unsigned int, f);
  u = (u + 0x7FFFu + ((u >> 16) & 1u)) >> 16;
  return (unsigned short)u;
}
__device__ __forceinline__ float b2f(unsigned short h){
  unsigned int u = ((unsigned int)h) << 16;
  return __builtin_bit_cast(float, u);
}
// fragment-major packed offset: (n,k) with K/32 = ksteps.
__device__ __forceinline__ size_t pk(int n, int k, int ksteps){
  return ((size_t)((n >> 4)*ksteps + (k >> 5))*64 + ((k >> 3) & 3)*16 + (n & 15))*8 + (k & 7);
}

__global__ void embed_k(const int* __restrict__ ids, const float* __restrict__ emb,
                        const float* __restrict__ pos, float* __restrict__ x){
  int row = blockIdx.x;          // b*SEQ + l
  int l = row % SEQ;
  int t = threadIdx.x;
  int id = ids[row];
  x[(size_t)row*HID + t] = emb[(size_t)id*HID + t] + pos[l*HID + t];
}

// split W1/W2 into bf16 hi/lo pairs, fragment-major packed.
__global__ void cvtw2_k(const float* __restrict__ W1, const float* __restrict__ W2,
                        unsigned short* __restrict__ W1h, unsigned short* __restrict__ W1l,
                        unsigned short* __restrict__ W2h, unsigned short* __restrict__ W2l){
  int i = blockIdx.x*256 + threadIdx.x;   // 0..131071
  {
    int l = i >> 16, rc = i & 65535;
    int n = rc >> 7, k = rc & 127;          // W1 [512][128]
    float w = W1[i];
    unsigned short h = f2b(w);
    size_t off = (size_t)l*65536 + pk(n, k, 4);
    W1h[off] = h; W1l[off] = f2b(w - b2f(h));
  }
  {
    int l = i >> 16, rc = i & 65535;
    int n = rc >> 9, k = rc & 511;          // W2 [128][512]
    float w = W2[i];
    unsigned short h = f2b(w);
    size_t off = (size_t)l*65536 + pk(n, k, 16);
    W2h[off] = h; W2l[off] = f2b(w - b2f(h));
  }
}

// Wq/Wk/Wv stacked [2][384][128] packed; Wo [2][128][128] packed.
__global__ void cvtw_qkvo_k(const float* __restrict__ Wq, const float* __restrict__ Wk,
                            const float* __restrict__ Wv, const float* __restrict__ Wo,
                            unsigned short* __restrict__ dst){
  int i = blockIdx.x*256 + threadIdx.x;   // 0..32767
  int l = i >> 14;
  int rc = i & 16383;
  int r = rc >> 7, k = rc & 127;
  unsigned short* Wqkvh = dst;
  unsigned short* Wqkvl = dst + 98304;
  unsigned short* Woh   = dst + 196608;
  unsigned short* Wol   = dst + 229376;
  size_t base = (size_t)l*49152;
  float w; unsigned short h;
  w = Wq[i]; h = f2b(w);
  { size_t o = base + pk(r, k, 4);        Wqkvh[o] = h; Wqkvl[o] = f2b(w - b2f(h)); }
  w = Wk[i]; h = f2b(w);
  { size_t o = base + pk(128 + r, k, 4);  Wqkvh[o] = h; Wqkvl[o] = f2b(w - b2f(h)); }
  w = Wv[i]; h = f2b(w);
  { size_t o = base + pk(256 + r, k, 4);  Wqkvh[o] = h; Wqkvl[o] = f2b(w - b2f(h)); }
  w = Wo[i]; h = f2b(w);
  { size_t o = (size_t)l*16384 + pk(r, k, 4); Woh[o] = h; Wol[o] = f2b(w - b2f(h)); }
}

// mixW [2][128][256] -> hi/lo packed (ksteps=8)
__global__ void cvtmix_k(const float* __restrict__ mixW,
                         unsigned short* __restrict__ mWh, unsigned short* __restrict__ mWl){
  int i = blockIdx.x*256 + threadIdx.x;   // 0..65535
  int l = i >> 15, rc = i & 32767;
  int n = rc >> 8, k = rc & 255;
  float w = mixW[i];
  unsigned short h = f2b(w);
  size_t off = (size_t)l*32768 + pk(n, k, 8);
  mWh[off] = h; mWl[off] = f2b(w - b2f(h));
}

// sess plain hi/lo; emb packed hi/lo (zero-padded to NPAD3, ksteps=4).
__global__ void cvt_logits_k(const float* __restrict__ sess, const float* __restrict__ emb,
                             unsigned short* __restrict__ sessH, unsigned short* __restrict__ sessL,
                             unsigned short* __restrict__ embH, unsigned short* __restrict__ embL){
  int i = blockIdx.x*256 + threadIdx.x;   // 0 .. NPAD3*128-1
  int n = i >> 7, k = i & 127;
  float w = (n < NOUT) ? emb[(size_t)(1+n)*HID + k] : 0.f;
  unsigned short h = f2b(w);
  size_t off = pk(n, k, 4);
  embH[off] = h; embL[off] = f2b(w - b2f(h));
  if (i < BSZ*HID){
    float s = sess[i];
    unsigned short hs = f2b(s);
    sessH[i] = hs; sessL[i] = f2b(s - b2f(hs));
  }
}

// mix via MFMA: one block per batch elem (R11 structure; GEMM2 weights packed).
__global__ __launch_bounds__(256) void mix_mfma_k(
    const float* __restrict__ A, const float* __restrict__ x,
    const unsigned short* __restrict__ mWh, const unsigned short* __restrict__ mWl,
    const float* __restrict__ mixb, float* __restrict__ xout)
{
  __shared__ __align__(16) char smem[65536];
  char* xTh = smem;
  char* xTl = smem + 16384;
  char* Ah  = smem + 32768;
  char* Al  = smem + 49152;
  char* Ch  = smem;
  char* Cl  = smem + 32768;

  int t = threadIdx.x;
  int wave = t >> 6, lane = t & 63;
  int g = lane >> 4, c16 = lane & 15;
  int b = blockIdx.x;
  size_t xbase = (size_t)b * SEQ * HID;

  {
    s16x8 z = {0,0,0,0,0,0,0,0};
    #pragma unroll
    for (int it = 0; it < 16; ++it)
      *(s16x8*)(smem + (it*256 + t)*16) = z;
  }
  __syncthreads();

  for (int task = t; task < SEQ*32; task += 256){
    int r = task >> 5, c4 = task & 31;
    float4 v = *(const float4*)(x + xbase + (size_t)r*HID + c4*4);
    float f[4] = {v.x, v.y, v.z, v.w};
    #pragma unroll
    for (int i = 0; i < 4; ++i){
      int d = c4*4 + i;
      unsigned short hi = f2b(f[i]);
      unsigned short lo = f2b(f[i] - b2f(hi));
      int off = d*128 + ((((r >> 3) ^ (d & 7))<<4)) + (r & 7)*2;
      *(unsigned short*)(xTh + off) = hi;
      *(unsigned short*)(xTl + off) = lo;
    }
  }
  {
    int l = t >> 2, q = t & 3;
    if (l < SEQ){
      const float* Ar = A + (size_t)(b*SEQ + l)*100;
      for (int j = q*25; j < q*25 + 25; ++j){
        float av = Ar[j];
        int col = (j < SEQ) ? j : (64 + (j - SEQ));
        unsigned short hi = f2b(av);
        unsigned short lo = f2b(av - b2f(hi));
        int off = l*256 + ((((col >> 3) ^ (l & 15))<<4)) + (col & 7)*2;
        *(unsigned short*)(Ah + off) = hi;
        *(unsigned short*)(Al + off) = lo;
      }
    }
  }
  __syncthreads();

  int rA = wave*16 + c16;
  s16x8 aih[2], ail[2], aoh[2], aol[2];
  #pragma unroll
  for (int kt = 0; kt < 2; ++kt){
    int ci = kt*4 + g;
    int co = 8 + kt*4 + g;
    int offi = rA*256 + ((ci ^ (rA & 15))<<4);
    int offo = rA*256 + ((co ^ (rA & 15))<<4);
    aih[kt] = *(const s16x8*)(Ah + offi);
    ail[kt] = *(const s16x8*)(Al + offi);
    aoh[kt] = *(const s16x8*)(Ah + offo);
    aol[kt] = *(const s16x8*)(Al + offo);
  }
  f32x4 accin[8], accout[8];
  #pragma unroll
  for (int nt = 0; nt < 8; ++nt){ accin[nt] = (f32x4){0,0,0,0}; accout[nt] = (f32x4){0,0,0,0}; }
  #pragma unroll
  for (int kt = 0; kt < 2; ++kt){
    #pragma unroll
    for (int nt = 0; nt < 8; ++nt){
      int d = nt*16 + c16;
      int boff = d*128 + ((((kt*4 + g) ^ (d & 7)))<<4);
      s16x8 bh = *(const s16x8*)(xTh + boff);
      s16x8 bl = *(const s16x8*)(xTl + boff);
      accin[nt]  = __builtin_amdgcn_mfma_f32_16x16x32_bf16(aih[kt], bh, accin[nt], 0,0,0);
      accin[nt]  = __builtin_amdgcn_mfma_f32_16x16x32_bf16(aih[kt], bl, accin[nt], 0,0,0);
      accin[nt]  = __builtin_amdgcn_mfma_f32_16x16x32_bf16(ail[kt], bh, accin[nt], 0,0,0);
      accout[nt] = __builtin_amdgcn_mfma_f32_16x16x32_bf16(aoh[kt], bh, accout[nt], 0,0,0);
      accout[nt] = __builtin_amdgcn_mfma_f32_16x16x32_bf16(aoh[kt], bl, accout[nt], 0,0,0);
      accout[nt] = __builtin_amdgcn_mfma_f32_16x16x32_bf16(aol[kt], bh, accout[nt], 0,0,0);
    }
  }
  __syncthreads();

  #pragma unroll
  for (int nt = 0; nt < 8; ++nt){
    #pragma unroll
    for (int r = 0; r < 4; ++r){
      int l = wave*16 + g*4 + r;
      int ci_ = nt*16 + c16;
      float vi = accin[nt][r];
      unsigned short hi = f2b(vi);
      int offi = l*512 + (((ci_ >> 3) ^ (l & 15))<<4) + (ci_ & 7)*2;
      *(unsigned short*)(Ch + offi) = hi;
      *(unsigned short*)(Cl + offi) = f2b(vi - b2f(hi));
      int co_ = 128 + nt*16 + c16;
      float vo = accout[nt][r];
      unsigned short ho = f2b(vo);
      int offo = l*512 + (((co_ >> 3) ^ (l & 15))<<4) + (co_ & 7)*2;
      *(unsigned short*)(Ch + offo) = ho;
      *(unsigned short*)(Cl + offo) = f2b(vo - b2f(ho));
    }
  }
  __syncthreads();

  int rc = wave*16 + c16;
  f32x4 acc2[8];
  #pragma unroll
  for (int nt = 0; nt < 8; ++nt) acc2[nt] = (f32x4){0,0,0,0};
  for (int kt2 = 0; kt2 < 8; ++kt2){
    int slot = (kt2*4 + g) ^ (rc & 15);
    s16x8 cfh = *(const s16x8*)(Ch + rc*512 + slot*16);
    s16x8 cfl = *(const s16x8*)(Cl + rc*512 + slot*16);
    #pragma unroll
    for (int nt = 0; nt < 8; ++nt){
      s16x8 wh = *(const s16x8*)(mWh + (size_t)(nt*8 + kt2)*512 + lane*8);
      s16x8 wl = *(const s16x8*)(mWl + (size_t)(nt*8 + kt2)*512 + lane*8);
      acc2[nt] = __builtin_amdgcn_mfma_f32_16x16x32_bf16(cfh, wh, acc2[nt], 0,0,0);
      acc2[nt] = __builtin_amdgcn_mfma_f32_16x16x32_bf16(cfh, wl, acc2[nt], 0,0,0);
      acc2[nt] = __builtin_amdgcn_mfma_f32_16x16x32_bf16(cfl, wh, acc2[nt], 0,0,0);
    }
  }
  #pragma unroll
  for (int nt = 0; nt < 8; ++nt){
    int j = nt*16 + c16;
    float bb = mixb[j];
    #pragma unroll
    for (int r = 0; r < 4; ++r){
      int l = wave*16 + g*4 + r;
      if (l < SEQ) xout[xbase + (size_t)l*HID + j] = acc2[nt][r] + bb;
    }
  }
}

// QKV projection: 64 rows/block, packed weight frags (proven R20).
__global__ __launch_bounds__(256) void qkv_mfma_k(
    const float* __restrict__ x,
    const unsigned short* __restrict__ Wh, const unsigned short* __restrict__ Wl,
    const float* __restrict__ bq, const float* __restrict__ bk,
    const float* __restrict__ bv, float* __restrict__ qkv)
{
  __shared__ unsigned short Xh[64*128];
  __shared__ unsigned short Xl[64*128];
  int t = threadIdx.x;
  int wave = t >> 6, lane = t & 63;
  int g = lane >> 4, c16 = lane & 15;
  int wrh = wave >> 1;
  int wn  = wave & 1;
  size_t row0 = (size_t)blockIdx.x * 64;

  #pragma unroll
  for (int it = 0; it < 4; ++it){
    int idx8 = it*256 + t;
    int r = idx8 >> 4;
    int c8 = idx8 & 15;
    const float* src = x + (row0 + r)*HID + c8*8;
    float4 v0 = *(const float4*)(src);
    float4 v1 = *(const float4*)(src + 4);
    float f[8] = {v0.x,v0.y,v0.z,v0.w,v1.x,v1.y,v1.z,v1.w};
    s16x8 ph, pl;
    #pragma unroll
    for (int e = 0; e < 8; ++e){
      unsigned short hi = f2b(f[e]);
      ph[e] = (short)hi;
      pl[e] = (short)f2b(f[e] - b2f(hi));
    }
    int slot = c8 ^ (r & 15);
    *(s16x8*)((char*)Xh + r*256 + slot*16) = ph;
    *(s16x8*)((char*)Xl + r*256 + slot*16) = pl;
  }
  __syncthreads();

  int rl0 = wrh*16 + c16;
  int rl1 = 32 + rl0;
  s16x8 a0h[4], a0l[4], a1h[4], a1l[4];
  #pragma unroll
  for (int kt = 0; kt < 4; ++kt){
    int slot = (kt*4 + g) ^ (rl0 & 15);
    a0h[kt] = *(const s16x8*)((const char*)Xh + rl0*256 + slot*16);
    a0l[kt] = *(const s16x8*)((const char*)Xl + rl0*256 + slot*16);
    a1h[kt] = *(const s16x8*)((const char*)Xh + rl1*256 + slot*16);
    a1l[kt] = *(const s16x8*)((const char*)Xl + rl1*256 + slot*16);
  }

  for (int nt = 0; nt < 12; ++nt){
    int tile = wn*12 + nt;
    int ncol = tile*16 + c16;          // 0..383
    f32x4 acc0 = {0.f,0.f,0.f,0.f};
    f32x4 acc1 = {0.f,0.f,0.f,0.f};
    #pragma unroll
    for (int kt = 0; kt < 4; ++kt){
      s16x8 bh = *(const s16x8*)(Wh + (size_t)(tile*4 + kt)*512 + lane*8);
      s16x8 bl = *(const s16x8*)(Wl + (size_t)(tile*4 + kt)*512 + lane*8);
      acc0 = __builtin_amdgcn_mfma_f32_16x16x32_bf16(a0h[kt], bh, acc0, 0,0,0);
      acc0 = __builtin_amdgcn_mfma_f32_16x16x32_bf16(a0h[kt], bl, acc0, 0,0,0);
      acc0 = __builtin_amdgcn_mfma_f32_16x16x32_bf16(a0l[kt], bh, acc0, 0,0,0);
      acc1 = __builtin_amdgcn_mfma_f32_16x16x32_bf16(a1h[kt], bh, acc1, 0,0,0);
      acc1 = __builtin_amdgcn_mfma_f32_16x16x32_bf16(a1h[kt], bl, acc1, 0,0,0);
      acc1 = __builtin_amdgcn_mfma_f32_16x16x32_bf16(a1l[kt], bh, acc1, 0,0,0);
    }
    int mat = ncol >> 7;
    int colin = ncol & 127;
    float bias = (mat == 0) ? bq[colin] : (mat == 1 ? bk[colin] : bv[colin]);
    #pragma unroll
    for (int r = 0; r < 4; ++r){
      int m = wrh*16 + g*4 + r;
      qkv[(row0 + m)*384 + ncol] = acc0[r] + bias;
      qkv[(row0 + 32 + m)*384 + ncol] = acc1[r] + bias;
    }
  }
}

// Attention core: +1-padded LDS rows to kill the 32-way bank conflict
// (qs/ks/vs stride 33 floats; ss stride 53). Math identical.
__global__ void attn_core_k(const float* __restrict__ qkv, float* __restrict__ o){
  int blk = blockIdx.x; int b = blk / NHEAD; int h = blk % NHEAD;
  int t = threadIdx.x;
  __shared__ float qs[SEQ][HDIM+1];
  __shared__ float ks[SEQ][HDIM+1];
  __shared__ float vs[SEQ][HDIM+1];
  __shared__ float ss[SEQ][SEQ+3];
  size_t base = (size_t)b*SEQ*384 + h*HDIM;
  for (int task = t; task < SEQ*HDIM; task += 256){
    int l = task >> 5, d = task & 31;
    const float* p = qkv + base + (size_t)l*384 + d;
    qs[l][d] = p[0];
    ks[l][d] = p[128];
    vs[l][d] = p[256];
  }
  __syncthreads();
  for (int task = t; task < SEQ*SEQ; task += 256){
    int l = task / SEQ, m = task % SEQ;
    float a = 0.f;
    #pragma unroll
    for (int d = 0; d < HDIM; ++d) a += qs[l][d]*ks[m][d];
    ss[l][m] = a * 0.17677669529663687f;  // 1/sqrt(32)
  }
  __syncthreads();
  if (t < SEQ){
    float mx = -1e30f;
    for (int m = 0; m < SEQ; ++m) mx = fmaxf(mx, ss[t][m]);
    float sum = 0.f;
    for (int m = 0; m < SEQ; ++m){ float e = __expf(ss[t][m]-mx); ss[t][m]=e; sum+=e; }
    float inv = 1.f/sum;
    for (int m = 0; m < SEQ; ++m) ss[t][m] *= inv;
  }
  __syncthreads();
  for (int task = t; task < SEQ*HDIM; task += 256){
    int l = task >> 5, d = task & 31;
    float a = 0.f;
    for (int m = 0; m < SEQ; ++m) a += ss[l][m]*vs[m][d];
    o[((size_t)b*SEQ+l)*HID + h*HDIM + d] = a;
  }
}

// O @ Wo^T + bo + residual + LN1: 64 rows/block, packed Wo frags (proven R20).
__global__ __launch_bounds__(256) void oproj_mfma_k(
    const float* __restrict__ o,
    const unsigned short* __restrict__ Woh_, const unsigned short* __restrict__ Wol_,
    const float* __restrict__ bo, const float* __restrict__ g1,
    const float* __restrict__ be1, float* x)
{
  __shared__ unsigned short Oh[64*128];
  __shared__ unsigned short Ol[64*128];
  __shared__ float red_s[2][2][2][16];
  __shared__ float red_q[2][2][2][16];
  int t = threadIdx.x;
  int wave = t >> 6, lane = t & 63;
  int g = lane >> 4, c16 = lane & 15;
  int wrh = wave >> 1;
  int wn  = wave & 1;
  size_t row0 = (size_t)blockIdx.x * 64;

  #pragma unroll
  for (int it = 0; it < 4; ++it){
    int idx8 = it*256 + t;
    int r = idx8 >> 4;
    int c8 = idx8 & 15;
    const float* src = o + (row0 + r)*HID + c8*8;
    float4 v0 = *(const float4*)(src);
    float4 v1 = *(const float4*)(src + 4);
    float f[8] = {v0.x,v0.y,v0.z,v0.w,v1.x,v1.y,v1.z,v1.w};
    s16x8 ph, pl;
    #pragma unroll
    for (int e = 0; e < 8; ++e){
      unsigned short hi = f2b(f[e]);
      ph[e] = (short)hi;
      pl[e] = (short)f2b(f[e] - b2f(hi));
    }
    int slot = c8 ^ (r & 15);
    *(s16x8*)((char*)Oh + r*256 + slot*16) = ph;
    *(s16x8*)((char*)Ol + r*256 + slot*16) = pl;
  }
  __syncthreads();

  int rl0 = wrh*16 + c16;
  int rl1 = 32 + rl0;
  s16x8 a0h[4], a0l[4], a1h[4], a1l[4];
  #pragma unroll
  for (int kt = 0; kt < 4; ++kt){
    int slot = (kt*4 + g) ^ (rl0 & 15);
    a0h[kt] = *(const s16x8*)((const char*)Oh + rl0*256 + slot*16);
    a0l[kt] = *(const s16x8*)((const char*)Ol + rl0*256 + slot*16);
    a1h[kt] = *(const s16x8*)((const char*)Oh + rl1*256 + slot*16);
    a1l[kt] = *(const s16x8*)((const char*)Ol + rl1*256 + slot*16);
  }

  float vals[2][4][4];
  #pragma unroll
  for (int nt = 0; nt < 4; ++nt){
    int tile = wn*4 + nt;
    int jcol = tile*16 + c16;
    f32x4 acc0 = {0.f,0.f,0.f,0.f};
    f32x4 acc1 = {0.f,0.f,0.f,0.f};
    #pragma unroll
    for (int kt = 0; kt < 4; ++kt){
      s16x8 bh = *(const s16x8*)(Woh_ + (size_t)(tile*4 + kt)*512 + lane*8);
      s16x8 bl = *(const s16x8*)(Wol_ + (size_t)(tile*4 + kt)*512 + lane*8);
      acc0 = __builtin_amdgcn_mfma_f32_16x16x32_bf16(a0h[kt], bh, acc0, 0,0,0);
      acc0 = __builtin_amdgcn_mfma_f32_16x16x32_bf16(a0h[kt], bl, acc0, 0,0,0);
      acc0 = __builtin_amdgcn_mfma_f32_16x16x32_bf16(a0l[kt], bh, acc0, 0,0,0);
      acc1 = __builtin_amdgcn_mfma_f32_16x16x32_bf16(a1h[kt], bh, acc1, 0,0,0);
      acc1 = __builtin_amdgcn_mfma_f32_16x16x32_bf16(a1h[kt], bl, acc1, 0,0,0);
      acc1 = __builtin_amdgcn_mfma_f32_16x16x32_bf16(a1l[kt], bh, acc1, 0,0,0);
    }
    float bias = bo[jcol];
    #pragma unroll
    for (int r = 0; r < 4; ++r){
      int m = wrh*16 + g*4 + r;
      vals[0][nt][r] = acc0[r] + bias + x[(row0 + m)*HID + jcol];
      vals[1][nt][r] = acc1[r] + bias + x[(row0 + 32 + m)*HID + jcol];
    }
  }

  #pragma unroll
  for (int q_ = 0; q_ < 2; ++q_){
    #pragma unroll
    for (int r = 0; r < 4; ++r){
      float s_ = vals[q_][0][r] + vals[q_][1][r] + vals[q_][2][r] + vals[q_][3][r];
      float qq = vals[q_][0][r]*vals[q_][0][r] + vals[q_][1][r]*vals[q_][1][r]
               + vals[q_][2][r]*vals[q_][2][r] + vals[q_][3][r]*vals[q_][3][r];
      s_ += __shfl_xor(s_, 1, 64); qq += __shfl_xor(qq, 1, 64);
      s_ += __shfl_xor(s_, 2, 64); qq += __shfl_xor(qq, 2, 64);
      s_ += __shfl_xor(s_, 4, 64); qq += __shfl_xor(qq, 4, 64);
      s_ += __shfl_xor(s_, 8, 64); qq += __shfl_xor(qq, 8, 64);
      if (c16 == 0){
        red_s[q_][wrh][wn][g*4 + r] = s_;
        red_q[q_][wrh][wn][g*4 + r] = qq;
      }
    }
  }
  __syncthreads();
  #pragma unroll
  for (int q_ = 0; q_ < 2; ++q_){
    #pragma unroll
    for (int r = 0; r < 4; ++r){
      int m = wrh*16 + g*4 + r;
      float s_tot = red_s[q_][wrh][0][g*4 + r] + red_s[q_][wrh][1][g*4 + r];
      float q_tot = red_q[q_][wrh][0][g*4 + r] + red_q[q_][wrh][1][g*4 + r];
      float mean = s_tot * (1.f/HID);
      float var = q_tot * (1.f/HID) - mean*mean;
      float rstd = rsqrtf(var + 1e-5f);
      #pragma unroll
      for (int nt = 0; nt < 4; ++nt){
        int jcol = (wn*4 + nt)*16 + c16;
        x[(row0 + q_*32 + m)*HID + jcol] = (vals[q_][nt][r]-mean)*rstd*g1[jcol] + be1[jcol];
      }
    }
  }
}

// FFN part 1: 64 rows/block, packed W1 frags; H written as PACKED bf16 hi/lo.
__global__ __launch_bounds__(256) void ffn1_k(
    const float* __restrict__ x,
    const unsigned short* __restrict__ W1h, const unsigned short* __restrict__ W1l,
    const float* __restrict__ b1,
    unsigned short* __restrict__ Hph, unsigned short* __restrict__ Hpl)
{
  __shared__ unsigned short Xh[64*128];
  __shared__ unsigned short Xl[64*128];
  int t = threadIdx.x;
  int wave = t >> 6, lane = t & 63;
  int g = lane >> 4, c16 = lane & 15;
  int wrh = wave >> 1;
  int wn  = wave & 1;
  size_t row0 = (size_t)blockIdx.x * 64;

  #pragma unroll
  for (int it = 0; it < 4; ++it){
    int idx8 = it*256 + t;
    int r = idx8 >> 4;
    int c8 = idx8 & 15;
    const float* src = x + (row0 + r)*HID + c8*8;
    float4 v0 = *(const float4*)(src);
    float4 v1 = *(const float4*)(src + 4);
    float f[8] = {v0.x,v0.y,v0.z,v0.w,v1.x,v1.y,v1.z,v1.w};
    s16x8 ph, pl;
    #pragma unroll
    for (int e = 0; e < 8; ++e){
      unsigned short hi = f2b(f[e]);
      ph[e] = (short)hi;
      pl[e] = (short)f2b(f[e] - b2f(hi));
    }
    int slot = c8 ^ (r & 15);
    *(s16x8*)((char*)Xh + r*256 + slot*16) = ph;
    *(s16x8*)((char*)Xl + r*256 + slot*16) = pl;
  }
  __syncthreads();

  int rl0 = wrh*16 + c16;
  int rl1 = 32 + rl0;
  s16x8 a0h[4], a0l[4], a1h[4], a1l[4];
  #pragma unroll
  for (int kt = 0; kt < 4; ++kt){
    int slot = (kt*4 + g) ^ (rl0 & 15);
    a0h[kt] = *(const s16x8*)((const char*)Xh + rl0*256 + slot*16);
    a0l[kt] = *(const s16x8*)((const char*)Xl + rl0*256 + slot*16);
    a1h[kt] = *(const s16x8*)((const char*)Xh + rl1*256 + slot*16);
    a1l[kt] = *(const s16x8*)((const char*)Xl + rl1*256 + slot*16);
  }

  for (int nt = 0; nt < 16; ++nt){
    int tile = wn*16 + nt;
    int ncol = tile*16 + c16;
    f32x4 acc0 = {0.f,0.f,0.f,0.f};
    f32x4 acc1 = {0.f,0.f,0.f,0.f};
    #pragma unroll
    for (int kt = 0; kt < 4; ++kt){
      s16x8 bh = *(const s16x8*)(W1h + (size_t)(tile*4 + kt)*512 + lane*8);
      s16x8 bl = *(const s16x8*)(W1l + (size_t)(tile*4 + kt)*512 + lane*8);
      acc0 = __builtin_amdgcn_mfma_f32_16x16x32_bf16(a0h[kt], bh, acc0, 0,0,0);
      acc0 = __builtin_amdgcn_mfma_f32_16x16x32_bf16(a0h[kt], bl, acc0, 0,0,0);
      acc0 = __builtin_amdgcn_mfma_f32_16x16x32_bf16(a0l[kt], bh, acc0, 0,0,0);
      acc1 = __builtin_amdgcn_mfma_f32_16x16x32_bf16(a1h[kt], bh, acc1, 0,0,0);
      acc1 = __builtin_amdgcn_mfma_f32_16x16x32_bf16(a1h[kt], bl, acc1, 0,0,0);
      acc1 = __builtin_amdgcn_mfma_f32_16x16x32_bf16(a1l[kt], bh, acc1, 0,0,0);
    }
    float bias = b1[ncol];
    #pragma unroll
    for (int r = 0; r < 4; ++r){
      int m0 = (int)row0 + wrh*16 + g*4 + r;
      float h0 = fmaxf(acc0[r] + bias, 0.f);
      unsigned short hh0 = f2b(h0);
      size_t o0 = pk(m0, ncol, 16);
      Hph[o0] = hh0; Hpl[o0] = f2b(h0 - b2f(hh0));
      float h1 = fmaxf(acc1[r] + bias, 0.f);
      unsigned short hh1 = f2b(h1);
      size_t o1 = pk(m0 + 32, ncol, 16);
      Hph[o1] = hh1; Hpl[o1] = f2b(h1 - b2f(hh1));
    }
  }
}

// FFN part 2: packed H + packed W2 frags direct from global (proven R21).
__global__ __launch_bounds__(256) void ffn2_k(
    const unsigned short* __restrict__ Hph, const unsigned short* __restrict__ Hpl,
    const unsigned short* __restrict__ W2h, const unsigned short* __restrict__ W2l,
    const float* __restrict__ b2, const float* __restrict__ gam,
    const float* __restrict__ bet, float* x)
{
  __shared__ float red_s[2][2][16];
  __shared__ float red_q[2][2][16];
  int t = threadIdx.x;
  int wave = t >> 6, lane = t & 63;
  int g = lane >> 4, c16 = lane & 15;
  int wrh = wave >> 1;
  int wn  = wave & 1;
  size_t row0 = (size_t)blockIdx.x * 32;
  int rt = (int)(row0 >> 4) + wrh;     // global 16-row tile of H

  f32x4 acc2[4];
  #pragma unroll
  for (int i = 0; i < 4; ++i) acc2[i] = (f32x4){0.f,0.f,0.f,0.f};
  for (int kt2 = 0; kt2 < 16; ++kt2){
    s16x8 hfh = *(const s16x8*)(Hph + (size_t)(rt*16 + kt2)*512 + lane*8);
    s16x8 hfl = *(const s16x8*)(Hpl + (size_t)(rt*16 + kt2)*512 + lane*8);
    #pragma unroll
    for (int nt2 = 0; nt2 < 4; ++nt2){
      int tile = wn*4 + nt2;
      s16x8 wfh = *(const s16x8*)(W2h + (size_t)(tile*16 + kt2)*512 + lane*8);
      s16x8 wfl = *(const s16x8*)(W2l + (size_t)(tile*16 + kt2)*512 + lane*8);
      acc2[nt2] = __builtin_amdgcn_mfma_f32_16x16x32_bf16(wfh, hfh, acc2[nt2], 0,0,0);
      acc2[nt2] = __builtin_amdgcn_mfma_f32_16x16x32_bf16(wfh, hfl, acc2[nt2], 0,0,0);
      acc2[nt2] = __builtin_amdgcn_mfma_f32_16x16x32_bf16(wfl, hfh, acc2[nt2], 0,0,0);
    }
  }

  int hrow = wrh*16 + c16;
  size_t grow = row0 + (size_t)hrow;
  const float* xr = x + grow*HID;
  float vals[16];
  float s = 0.f, q = 0.f;
  #pragma unroll
  for (int nt2 = 0; nt2 < 4; ++nt2){
    #pragma unroll
    for (int r = 0; r < 4; ++r){
      int j = (wn*4 + nt2)*16 + g*4 + r;
      float v = acc2[nt2][r] + b2[j] + xr[j];
      vals[nt2*4+r] = v;
      s += v; q += v*v;
    }
  }
  s += __shfl_xor(s, 16, 64);
  s += __shfl_xor(s, 32, 64);
  q += __shfl_xor(q, 16, 64);
  q += __shfl_xor(q, 32, 64);
  if (g == 0){
    red_s[wrh][wn][c16] = s;
    red_q[wrh][wn][c16] = q;
  }
  __syncthreads();
  float s_tot = red_s[wrh][0][c16] + red_s[wrh][1][c16];
  float q_tot = red_q[wrh][0][c16] + red_q[wrh][1][c16];
  float mean = s_tot * (1.f/HID);
  float var = q_tot * (1.f/HID) - mean*mean;
  float rstd = rsqrtf(var + 1e-5f);
  float* orow = x + grow*HID;
  #pragma unroll
  for (int nt2 = 0; nt2 < 4; ++nt2){
    #pragma unroll
    for (int r = 0; r < 4; ++r){
      int j = (wn*4 + nt2)*16 + g*4 + r;
      orow[j] = (vals[nt2*4+r]-mean)*rstd*gam[j] + bet[j];
    }
  }
}

// attention pooling + session vector (proven, unchanged).
__global__ void final_k(const float* __restrict__ x, const float* __restrict__ attW,
                        const float* __restrict__ attb, const float* __restrict__ sessW,
                        const float* __restrict__ sessb, float* __restrict__ sess){
  int b = blockIdx.x; int t = threadIdx.x;
  __shared__ float av[SEQ];
  __shared__ __align__(16) float cat[256];
  const float* xb = x + (size_t)b*SEQ*HID;
  if (t < SEQ){
    float a = attb[0];
    for (int c = 0; c < HID; ++c) a += xb[t*HID + c]*attW[c];
    av[t] = a;
  }
  __syncthreads();
  if (t == 0){
    float s = 0.f;
    for (int l = 0; l < SEQ; ++l) s += av[l];
    float inv = 1.f/s;
    for (int l = 0; l < SEQ; ++l) av[l] *= inv;
  }
  __syncthreads();
  float gacc = 0.f;
  for (int l = 0; l < SEQ; ++l) gacc += xb[l*HID + t]*av[l];
  cat[t] = xb[49*HID + t];
  cat[128+t] = gacc;
  __syncthreads();
  float acc = sessb[t];
  const float4* w = (const float4*)(sessW + (size_t)t*256);
  const float4* c4 = (const float4*)cat;
  #pragma unroll 8
  for (int j = 0; j < 64; ++j){
    float4 wv=w[j]; float4 cv=c4[j];
    acc += wv.x*cv.x + wv.y*cv.y + wv.z*cv.z + wv.w*cv.w;
  }
  sess[(size_t)b*HID + t] = acc;
}

// logits: XCD swizzle + two col-slabs + packed emb frags + LDS/NT stores.
__global__ __launch_bounds__(256) void logits_mfma_k(
    const unsigned short* __restrict__ sessH, const unsigned short* __restrict__ sessL,
    const unsigned short* __restrict__ embH, const unsigned short* __restrict__ embL,
    float* __restrict__ out)
{
  __shared__ unsigned short Sh[32*128];
  __shared__ unsigned short Sl[32*128];
  __shared__ float Ob[32*132];
  int t = threadIdx.x;
  int wave = t >> 6, lane = t & 63;
  int g = lane >> 4, c16 = lane & 15;
  int wrh = wave >> 1;
  int wn  = wave & 1;
  int id = blockIdx.x;             // 0..12799
  int xcd = id & 7;
  int j = id >> 3;
  int dslab = xcd*25 + (j >> 6);   // 0..199
  int rowt = j & 63;
  size_t row0 = (size_t)rowt * 32;

  #pragma unroll
  for (int it = 0; it < 2; ++it){
    int idx8 = it*256 + t;
    int r = idx8 >> 4;
    int c8 = idx8 & 15;
    s16x8 ph = *(const s16x8*)(sessH + (row0 + r)*HID + c8*8);
    s16x8 pl = *(const s16x8*)(sessL + (row0 + r)*HID + c8*8);
    int slot = c8 ^ (r & 15);
    *(s16x8*)((char*)Sh + r*256 + slot*16) = ph;
    *(s16x8*)((char*)Sl + r*256 + slot*16) = pl;
  }
  __syncthreads();

  int rloc = wrh*16 + c16;
  s16x8 afh[4], afl[4];
  #pragma unroll
  for (int kt = 0; kt < 4; ++kt){
    int slot = (kt*4 + g) ^ (rloc & 15);
    afh[kt] = *(const s16x8*)((const char*)Sh + rloc*256 + slot*16);
    afl[kt] = *(const s16x8*)((const char*)Sl + rloc*256 + slot*16);
  }

  #pragma unroll
  for (int ph = 0; ph < 2; ++ph){
    int n0 = dslab*256 + ph*128;
    #pragma unroll
    for (int nt = 0; nt < 4; ++nt){
      int tb = (n0 >> 4) + wn*4 + nt;
      int ncol = n0 + (wn*4 + nt)*16 + c16;
      f32x4 acc = {0.f,0.f,0.f,0.f};
      #pragma unroll
      for (int kt = 0; kt < 4; ++kt){
        s16x8 bh = *(const s16x8*)(embH + (size_t)(tb*4 + kt)*512 + lane*8);
        s16x8 bl = *(const s16x8*)(embL + (size_t)(tb*4 + kt)*512 + lane*8);
        acc = __builtin_amdgcn_mfma_f32_16x16x32_bf16(afh[kt], bh, acc, 0,0,0);
        acc = __builtin_amdgcn_mfma_f32_16x16x32_bf16(afh[kt], bl, acc, 0,0,0);
        acc = __builtin_amdgcn_mfma_f32_16x16x32_bf16(afl[kt], bh, acc, 0,0,0);
      }
      #pragma unroll
      for (int r = 0; r < 4; ++r){
        int m = wrh*16 + g*4 + r;
        Ob[m*132 + (wn*4 + nt)*16 + c16] = acc[r];
      }
    }
    __syncthreads();

    #pragma unroll
    for (int k = 0; k < 16; ++k){
      int idx = k*256 + t;
      int r_ = idx >> 7;
      int c_ = idx & 127;
      int ncol = n0 + c_;
      if (ncol < NOUT){
        __builtin_nontemporal_store(Ob[r_*132 + c_],
                                    out + (row0 + r_)*(size_t)NOUT + ncol);
      }
    }
    __syncthreads();
  }
}

extern "C" void kernel_launch(void* const* d_in, const int* in_sizes, int n_in,
                              void* d_out, int out_size, void* d_ws, size_t ws_size,
                              hipStream_t stream){
  const int*   ids  = (const int*)d_in[0];
  const float* A    = (const float*)d_in[1];
  const float* emb  = (const float*)d_in[2];
  const float* pos  = (const float*)d_in[3];
  const float* mixW = (const float*)d_in[4];
  const float* mixb = (const float*)d_in[5];
  const float* Wq   = (const float*)d_in[6];
  const float* bq   = (const float*)d_in[7];
  const float* Wk   = (const float*)d_in[8];
  const float* bk   = (const float*)d_in[9];
  const float* Wv   = (const float*)d_in[10];
  const float* bv   = (const float*)d_in[11];
  const float* Wo   = (const float*)d_in[12];
  const float* bo   = (const float*)d_in[13];
  const float* ln1g = (const float*)d_in[14];
  const float* ln1b = (const float*)d_in[15];
  const float* W1   = (const float*)d_in[16];
  const float* b1   = (const float*)d_in[17];
  const float* W2   = (const float*)d_in[18];
  const float* b2   = (const float*)d_in[19];
  const float* ln2g = (const float*)d_in[20];
  const float* ln2b = (const float*)d_in[21];
  const float* attW = (const float*)d_in[22];
  const float* attb = (const float*)d_in[23];
  const float* sessW= (const float*)d_in[24];
  const float* sessb= (const float*)d_in[25];
  float* out = (float*)d_out;

  float* xA   = (float*)d_ws;
  float* xB   = xA + (size_t)BSZ*SEQ*HID;
  float* sess = xB + (size_t)BSZ*SEQ*HID;
  unsigned short* W1h = (unsigned short*)sess;
  unsigned short* W1l = W1h + (size_t)2*INNER*HID;
  unsigned short* W2h = W1l + (size_t)2*INNER*HID;
  unsigned short* W2l = W2h + (size_t)2*INNER*HID;
  unsigned short* awb = (unsigned short*)(out + (size_t)out_size - 131072);
  unsigned short* Wqkvh = awb;
  unsigned short* Wqkvl = awb + 98304;
  unsigned short* Woh   = awb + 196608;
  unsigned short* Wol   = awb + 229376;
  unsigned short* mwb = (unsigned short*)(out + (size_t)out_size - 131072 - 65536);
  unsigned short* mWh = mwb;
  unsigned short* mWl = mwb + 65536;
  float* qkvbuf = out;                               // 102400*384 floats
  float* obuf   = out + (size_t)102400*384;          // 102400*128 floats
  unsigned short* Hph = (unsigned short*)out;        // 102400*512 ushorts (qkv/o dead)
  unsigned short* Hpl = Hph + (size_t)102400*INNER;
  unsigned short* embHs = (unsigned short*)xB;
  unsigned short* embLs = embHs + (size_t)NPAD3*HID;
  unsigned short* sessH = embLs + (size_t)NPAD3*HID;
  unsigned short* sessL = sessH + (size_t)BSZ*HID;

  cvtw2_k<<<512, 256, 0, stream>>>(W1, W2, W1h, W1l, W2h, W2l);
  cvtw_qkvo_k<<<128, 256, 0, stream>>>(Wq, Wk, Wv, Wo, awb);
  cvtmix_k<<<256, 256, 0, stream>>>(mixW, mWh, mWl);
  embed_k<<<BSZ*SEQ, HID, 0, stream>>>(ids, emb, pos, xA);
  float* xc = xA; float* xn = xB;
  for (int i = 0; i < 2; ++i){
    mix_mfma_k<<<BSZ, 256, 0, stream>>>(A, xc,
        mWh + (size_t)i*HID*256, mWl + (size_t)i*HID*256, mixb + i*HID, xn);
    qkv_mfma_k<<<BSZ*SEQ/64, 256, 0, stream>>>(xn,
        Wqkvh + (size_t)i*384*HID, Wqkvl + (size_t)i*384*HID,
        bq + i*HID, bk + i*HID, bv + i*HID, qkvbuf);
    attn_core_k<<<BSZ*NHEAD, 256, 0, stream>>>(qkvbuf, obuf);
    oproj_mfma_k<<<BSZ*SEQ/64, 256, 0, stream>>>(obuf,
        Woh + (size_t)i*HID*HID, Wol + (size_t)i*HID*HID,
        bo + i*HID, ln1g + i*HID, ln1b + i*HID, xn);
    ffn1_k<<<BSZ*SEQ/64, 256, 0, stream>>>(xn,
        W1h + (size_t)i*INNER*HID, W1l + (size_t)i*INNER*HID, b1 + i*INNER,
        Hph, Hpl);
    ffn2_k<<<BSZ*SEQ/32, 256, 0, stream>>>(Hph, Hpl,
        W2h + (size_t)i*INNER*HID, W2l + (size_t)i*INNER*HID, b2 + i*HID,
        ln2g + i*HID, ln2b + i*HID, xn);
    float* tmp = xc; xc = xn; xn = tmp;
  }
  final_k<<<BSZ, HID, 0, stream>>>(xc, attW, attb, sessW, sessb, sess);
  cvt_logits_k<<<NPAD3*HID/256, 256, 0, stream>>>(sess, emb, sessH, sessL, embHs, embLs);
  logits_mfma_k<<<8*25*64, 256, 0, stream>>>(sessH, sessL, embHs, embLs, out);
}